// Round 4
// baseline (1053.633 us; speedup 1.0000x reference)
//
#include <hip/hip_runtime.h>
#include <math.h>

#define BB 4
#define NN 2048
#define KK 20

static __device__ __forceinline__ float lrelu(float z) {
    return z >= 0.f ? z : 0.2f * z;
}

// ---------------- sq: per-point squared norm ----------------
template<int C>
__global__ __launch_bounds__(256) void sq_kernel(const float* __restrict__ x,
                                                 float* __restrict__ sq) {
    int i = blockIdx.x * 256 + threadIdx.x;
    if (i >= BB * NN) return;
    int b = i / NN, n = i - b * NN;
    const float* xb = x + (size_t)b * C * NN + n;
    float s = 0.f;
    #pragma unroll
    for (int c = 0; c < C; ++c) {
        float v = xb[(size_t)c * NN];
        s = fmaf(v, v, s);
    }
    sq[i] = s;
}

// ---------------- knn: top-20 smallest distance indices ----------------
// Block = 512 threads (8 waves) handles (b, 8 consecutive queries); each wave
// owns ONE query -> single selection pass (was 2 sequential passes).
// Distances -> monotone u32 keys (order == float order; -0.0 impossible) so
// selection is integer min with shallow chains:
//   local (key,slot) tree (depth 5, tie->left=smaller j)
//   u32 key butterfly + enc=(slot<<6)|lane butterfly (smallest j on ties)
// Exact (d, j) lexicographic semantics — matches lax.top_k.
template<int C>
__global__ __launch_bounds__(512, 4) void knn_kernel(const float* __restrict__ x,
                                                     const float* __restrict__ sq,
                                                     int* __restrict__ idx) {
    const int QT = 8;
    __shared__ unsigned dl[QT][NN];   // 64 KB of keys
    __shared__ float xq[QT][C];
    __shared__ float sqq[QT];
    int blk = blockIdx.x;
    int b = blk / (NN / QT);
    int q0 = (blk - b * (NN / QT)) * QT;
    int t = threadIdx.x;
    int lane = t & 63, wid = t >> 6;

    const float* xb = x + (size_t)b * C * NN;
    for (int e = t; e < QT * C; e += 512) {
        int q = e / C, c = e - q * C;
        xq[q][c] = xb[(size_t)c * NN + q0 + q];
    }
    if (t < QT) sqq[t] = sq[b * NN + q0 + t];
    __syncthreads();

    float acc[QT][4];
    #pragma unroll
    for (int q = 0; q < QT; ++q)
        #pragma unroll
        for (int s = 0; s < 4; ++s) acc[q][s] = 0.f;

    for (int c = 0; c < C; ++c) {
        float xj[4];
        #pragma unroll
        for (int s = 0; s < 4; ++s) xj[s] = xb[(size_t)c * NN + t + s * 512];
        #pragma unroll
        for (int q = 0; q < QT; ++q) {
            float xqc = xq[q][c];
            #pragma unroll
            for (int s = 0; s < 4; ++s) acc[q][s] = fmaf(xqc, xj[s], acc[q][s]);
        }
    }
    float sqj[4];
    #pragma unroll
    for (int s = 0; s < 4; ++s) sqj[s] = sq[b * NN + t + s * 512];

    // d = sq_i + sq_j - 2*inner (same expression as R2/R3 — values bit-identical),
    // then monotone key transform.
    #pragma unroll
    for (int q = 0; q < QT; ++q) {
        float sqi = sqq[q];
        #pragma unroll
        for (int s = 0; s < 4; ++s) {
            float d = sqi + sqj[s] - 2.f * acc[q][s];
            unsigned u = __float_as_uint(d);
            dl[q][s * 512 + t] = u ^ ((unsigned)((int)u >> 31) | 0x80000000u);
        }
    }
    __syncthreads();

    // wave wid owns query q0+wid; lane holds candidates j = s2*64 + lane
    unsigned cand[32];
    #pragma unroll
    for (int s2 = 0; s2 < 32; ++s2)
        cand[s2] = dl[wid][s2 * 64 + lane];

    int* orow = idx + (size_t)(b * NN + q0 + wid) * KK;
    #pragma unroll 1
    for (int r = 0; r < KK; ++r) {
        // local argmin over 32 register candidates, (key, slot) tree, tie->left
        unsigned k[16]; int sl[16];
        #pragma unroll
        for (int i = 0; i < 16; ++i) {
            bool c2 = cand[i + 16] < cand[i];
            k[i] = c2 ? cand[i + 16] : cand[i];
            sl[i] = c2 ? i + 16 : i;
        }
        #pragma unroll
        for (int i = 0; i < 8; ++i) {
            bool c2 = k[i + 8] < k[i];
            k[i] = c2 ? k[i + 8] : k[i];
            sl[i] = c2 ? sl[i + 8] : sl[i];
        }
        #pragma unroll
        for (int i = 0; i < 4; ++i) {
            bool c2 = k[i + 4] < k[i];
            k[i] = c2 ? k[i + 4] : k[i];
            sl[i] = c2 ? sl[i + 4] : sl[i];
        }
        #pragma unroll
        for (int i = 0; i < 2; ++i) {
            bool c2 = k[i + 2] < k[i];
            k[i] = c2 ? k[i + 2] : k[i];
            sl[i] = c2 ? sl[i + 2] : sl[i];
        }
        bool c2 = k[1] < k[0];
        unsigned vk = c2 ? k[1] : k[0];
        int vs = c2 ? sl[1] : sl[0];

        // wave key min
        unsigned vg = vk;
        #pragma unroll
        for (int off = 32; off >= 1; off >>= 1) {
            unsigned o = (unsigned)__shfl_xor((int)vg, off);
            vg = vg < o ? vg : o;
        }
        // smallest j among key==vg (enc == j for valid; 4096+lane sentinel otherwise)
        int enc = (vk == vg) ? ((vs << 6) | lane) : (4096 | lane);
        #pragma unroll
        for (int off = 32; off >= 1; off >>= 1)
            enc = min(enc, __shfl_xor(enc, off));
        // winner lane (unique: low 6 bits embed source lane) invalidates its slot
        if ((enc & 63) == lane) {
            #pragma unroll
            for (int s2 = 0; s2 < 32; ++s2)
                if (s2 == vs) cand[s2] = 0xFFFFFFFFu;
        }
        if (lane == 0) orow[r] = enc;
    }
}

// ---------------- p/t: p = Wn·x, t = (Wc-Wn)·x ----------------
template<int C, int OT>
__global__ __launch_bounds__(256) void pt_kernel(const float* __restrict__ x,
                                                 const float* __restrict__ W,
                                                 float* __restrict__ p,
                                                 float* __restrict__ tt,
                                                 int O) {
    const int NB = NN / 256;
    int blk = blockIdx.x;
    int nb = blk % NB;
    int rest = blk / NB;
    int nob = O / OT;
    int ob = rest % nob;
    int b = rest / nob;
    int t = threadIdx.x;
    int n = nb * 256 + t;
    __shared__ float wn[OT][C], wd[OT][C];
    for (int e = t; e < OT * C; e += 256) {
        int o = e / C, c = e - o * C;
        float a = W[(size_t)(ob * OT + o) * (2 * C) + c];
        float b2 = W[(size_t)(ob * OT + o) * (2 * C) + C + c];
        wn[o][c] = a;
        wd[o][c] = b2 - a;
    }
    __syncthreads();
    float ap[OT], at[OT];
    #pragma unroll
    for (int o = 0; o < OT; ++o) { ap[o] = 0.f; at[o] = 0.f; }
    const float* xb = x + (size_t)b * C * NN + n;
    for (int c = 0; c < C; ++c) {
        float xv = xb[(size_t)c * NN];
        #pragma unroll
        for (int o = 0; o < OT; ++o) {
            ap[o] = fmaf(wn[o][c], xv, ap[o]);
            at[o] = fmaf(wd[o][c], xv, at[o]);
        }
    }
    size_t base = ((size_t)b * O + ob * OT) * NN + n;
    #pragma unroll
    for (int o = 0; o < OT; ++o) {
        p[base + (size_t)o * NN] = ap[o];
        tt[base + (size_t)o * NN] = at[o];
    }
}

// ---------------- edge max: out[b,o,i] = max_k lrelu(scale*(p[j]+t_i)+beta) ----------------
__global__ __launch_bounds__(256) void edge_kernel(const float* __restrict__ p,
                                                   const float* __restrict__ tt,
                                                   const int* __restrict__ idx,
                                                   const float* __restrict__ g,
                                                   const float* __restrict__ be,
                                                   float* __restrict__ out, int O) {
    int b = blockIdx.x / O, o = blockIdx.x - b * O;
    __shared__ float pl[NN];
    const float* pr = p + ((size_t)b * O + o) * NN;
    for (int e = threadIdx.x * 4; e < NN; e += 1024)
        *(float4*)&pl[e] = *(const float4*)&pr[e];
    __syncthreads();
    float scale = g[o] / sqrtf(1.f + 1e-5f);
    float beta = be[o];
    const float* tr = tt + ((size_t)b * O + o) * NN;
    float* orow = out + ((size_t)b * O + o) * NN;
    for (int i = threadIdx.x; i < NN; i += 256) {
        float ti = tr[i];
        const int4* ir4 = (const int4*)(idx + (size_t)(b * NN + i) * KK);
        int4 w0 = ir4[0], w1 = ir4[1], w2 = ir4[2], w3 = ir4[3], w4 = ir4[4];
        float m = -__builtin_inff();
        int js[20] = {w0.x, w0.y, w0.z, w0.w, w1.x, w1.y, w1.z, w1.w,
                      w2.x, w2.y, w2.z, w2.w, w3.x, w3.y, w3.z, w3.w,
                      w4.x, w4.y, w4.z, w4.w};
        #pragma unroll
        for (int k = 0; k < KK; ++k) {
            float y = pl[js[k]] + ti;
            m = fmaxf(m, lrelu(fmaf(scale, y, beta)));
        }
        orow[i] = m;
    }
}

// ---------------- transpose W5 [1024][256] -> W5T [256][1024] ----------------
__global__ __launch_bounds__(256) void transpose_kernel(const float* __restrict__ W,
                                                        float* __restrict__ WT) {
    __shared__ float tile[32][33];
    int c0 = blockIdx.x * 32, o0 = blockIdx.y * 32;
    int tx = threadIdx.x, ty = threadIdx.y;   // 32 x 8
    #pragma unroll
    for (int i = 0; i < 32; i += 8)
        tile[ty + i][tx] = W[(size_t)(o0 + ty + i) * 256 + c0 + tx];
    __syncthreads();
    #pragma unroll
    for (int i = 0; i < 32; i += 8)
        WT[(size_t)(c0 + ty + i) * 1024 + o0 + tx] = tile[tx][ty + i];
}

// ---------------- final: register-tiled GEMM + fused lrelu + max over n ----------------
__global__ __launch_bounds__(256) void final_kernel(const float* __restrict__ x4,
                                                    const float* __restrict__ W5T,
                                                    const float* __restrict__ g,
                                                    const float* __restrict__ be,
                                                    float* __restrict__ partial) {
    const int CC = 256;
    __shared__ float xs[64][64];
    __shared__ float ws[64][64];
    int blk = blockIdx.x;
    int nb = blk & 31;
    int ob = (blk >> 5) & 15;
    int b  = blk >> 9;
    int t = threadIdx.x;
    int tn = t & 15, to = t >> 4;

    float acc[4][4];
    #pragma unroll
    for (int i = 0; i < 4; ++i)
        #pragma unroll
        for (int j = 0; j < 4; ++j) acc[i][j] = 0.f;

    for (int c0 = 0; c0 < CC; c0 += 64) {
        __syncthreads();
        #pragma unroll
        for (int e = t * 4; e < 64 * 64; e += 1024) {
            int c = e >> 6, n = e & 63;
            *(float4*)&xs[c][n] =
                *(const float4*)&x4[((size_t)b * CC + c0 + c) * NN + nb * 64 + n];
        }
        #pragma unroll
        for (int e = t * 4; e < 64 * 64; e += 1024) {
            int c = e >> 6, o = e & 63;
            *(float4*)&ws[c][o] =
                *(const float4*)&W5T[(size_t)(c0 + c) * 1024 + ob * 64 + o];
        }
        __syncthreads();
        for (int c = 0; c < 64; ++c) {
            float4 xv = *(float4*)&xs[c][tn * 4];
            float4 wv = *(float4*)&ws[c][to * 4];
            acc[0][0] = fmaf(wv.x, xv.x, acc[0][0]);
            acc[0][1] = fmaf(wv.x, xv.y, acc[0][1]);
            acc[0][2] = fmaf(wv.x, xv.z, acc[0][2]);
            acc[0][3] = fmaf(wv.x, xv.w, acc[0][3]);
            acc[1][0] = fmaf(wv.y, xv.x, acc[1][0]);
            acc[1][1] = fmaf(wv.y, xv.y, acc[1][1]);
            acc[1][2] = fmaf(wv.y, xv.z, acc[1][2]);
            acc[1][3] = fmaf(wv.y, xv.w, acc[1][3]);
            acc[2][0] = fmaf(wv.z, xv.x, acc[2][0]);
            acc[2][1] = fmaf(wv.z, xv.y, acc[2][1]);
            acc[2][2] = fmaf(wv.z, xv.z, acc[2][2]);
            acc[2][3] = fmaf(wv.z, xv.w, acc[2][3]);
            acc[3][0] = fmaf(wv.w, xv.x, acc[3][0]);
            acc[3][1] = fmaf(wv.w, xv.y, acc[3][1]);
            acc[3][2] = fmaf(wv.w, xv.z, acc[3][2]);
            acc[3][3] = fmaf(wv.w, xv.w, acc[3][3]);
        }
    }

    float rs = 1.f / sqrtf(1.f + 1e-5f);
    #pragma unroll
    for (int i = 0; i < 4; ++i) {
        int o = ob * 64 + to * 4 + i;
        float scale = g[o] * rs, beta = be[o];
        float m = -__builtin_inff();
        #pragma unroll
        for (int j = 0; j < 4; ++j)
            m = fmaxf(m, lrelu(fmaf(scale, acc[i][j], beta)));
        #pragma unroll
        for (int off = 8; off >= 1; off >>= 1)
            m = fmaxf(m, __shfl_xor(m, off));
        if (tn == 0)
            partial[(size_t)(nb * BB + b) * 1024 + o] = m;
    }
}

__global__ __launch_bounds__(256) void reduce32_kernel(const float* __restrict__ partial,
                                                       float* __restrict__ out) {
    int i = blockIdx.x * 256 + threadIdx.x;
    if (i >= BB * 1024) return;
    int b = i >> 10, o = i & 1023;
    float m = -__builtin_inff();
    #pragma unroll
    for (int nb = 0; nb < 32; ++nb)
        m = fmaxf(m, partial[(size_t)(nb * BB + b) * 1024 + o]);
    out[i] = m;
}

extern "C" void kernel_launch(void* const* d_in, const int* in_sizes, int n_in,
                              void* d_out, int out_size, void* d_ws, size_t ws_size,
                              hipStream_t stream) {
    const float* x  = (const float*)d_in[0];
    const float* W1 = (const float*)d_in[1];
    const float* g1 = (const float*)d_in[2];
    const float* b1 = (const float*)d_in[3];
    const float* W2 = (const float*)d_in[4];
    const float* g2 = (const float*)d_in[5];
    const float* b2 = (const float*)d_in[6];
    const float* W3 = (const float*)d_in[7];
    const float* g3 = (const float*)d_in[8];
    const float* b3 = (const float*)d_in[9];
    const float* W4 = (const float*)d_in[10];
    const float* g4 = (const float*)d_in[11];
    const float* b4 = (const float*)d_in[12];
    const float* W5 = (const float*)d_in[13];
    const float* g5 = (const float*)d_in[14];
    const float* b5 = (const float*)d_in[15];

    float* ws = (float*)d_ws;
    float* sq      = ws;                       // 8192
    int*   idx     = (int*)(ws + 8192);        // 163840 ints
    float* x1      = ws + 8192 + 163840;       // 524288
    float* x2      = x1 + 524288;              // 524288
    float* x3      = x2 + 524288;              // 1048576
    float* x4      = x3 + 1048576;             // 2097152
    float* p       = x4 + 2097152;             // 2097152
    float* tt      = p + 2097152;              // 2097152
    float* W5T     = p;                        // reuse (dead after layer 4)
    float* partial = tt;                       // reuse

    dim3 blk(256), kblk(512);

    // ---- layer 1: C=3, O=64 ----
    sq_kernel<3><<<32, blk, 0, stream>>>(x, sq);
    knn_kernel<3><<<BB * (NN / 8), kblk, 0, stream>>>(x, sq, idx);
    pt_kernel<3, 16><<<BB * (64 / 16) * (NN / 256), blk, 0, stream>>>(x, W1, p, tt, 64);
    edge_kernel<<<BB * 64, blk, 0, stream>>>(p, tt, idx, g1, b1, x1, 64);

    // ---- layer 2: C=64, O=64 ----
    sq_kernel<64><<<32, blk, 0, stream>>>(x1, sq);
    knn_kernel<64><<<BB * (NN / 8), kblk, 0, stream>>>(x1, sq, idx);
    pt_kernel<64, 16><<<BB * (64 / 16) * (NN / 256), blk, 0, stream>>>(x1, W2, p, tt, 64);
    edge_kernel<<<BB * 64, blk, 0, stream>>>(p, tt, idx, g2, b2, x2, 64);

    // ---- layer 3: C=64, O=128 ----
    sq_kernel<64><<<32, blk, 0, stream>>>(x2, sq);
    knn_kernel<64><<<BB * (NN / 8), kblk, 0, stream>>>(x2, sq, idx);
    pt_kernel<64, 16><<<BB * (128 / 16) * (NN / 256), blk, 0, stream>>>(x2, W3, p, tt, 128);
    edge_kernel<<<BB * 128, blk, 0, stream>>>(p, tt, idx, g3, b3, x3, 128);

    // ---- layer 4: C=128, O=256 ----
    sq_kernel<128><<<32, blk, 0, stream>>>(x3, sq);
    knn_kernel<128><<<BB * (NN / 8), kblk, 0, stream>>>(x3, sq, idx);
    pt_kernel<128, 16><<<BB * (256 / 16) * (NN / 256), blk, 0, stream>>>(x3, W4, p, tt, 256);
    edge_kernel<<<BB * 256, blk, 0, stream>>>(p, tt, idx, g4, b4, x4, 256);

    // ---- layer 5: C=256, O=1024, fused max over n ----
    transpose_kernel<<<dim3(8, 32), dim3(32, 8), 0, stream>>>(W5, W5T);
    final_kernel<<<BB * 16 * 32, blk, 0, stream>>>(x4, W5T, g5, b5, partial);
    reduce32_kernel<<<16, blk, 0, stream>>>(partial, (float*)d_out);
}

// Round 6
// 864.534 us; speedup vs baseline: 1.2187x; 1.2187x over previous
//
#include <hip/hip_runtime.h>
#include <math.h>

#define BB 4
#define NN 2048
#define KK 20

static __device__ __forceinline__ float lrelu(float z) {
    return z >= 0.f ? z : 0.2f * z;
}

// ---------------- sq: per-point squared norm ----------------
template<int C>
__global__ __launch_bounds__(256) void sq_kernel(const float* __restrict__ x,
                                                 float* __restrict__ sq) {
    int i = blockIdx.x * 256 + threadIdx.x;
    if (i >= BB * NN) return;
    int b = i / NN, n = i - b * NN;
    const float* xb = x + (size_t)b * C * NN + n;
    float s = 0.f;
    #pragma unroll
    for (int c = 0; c < C; ++c) {
        float v = xb[(size_t)c * NN];
        s = fmaf(v, v, s);
    }
    sq[i] = s;
}

// ---------------- knn: top-20 smallest distance indices ----------------
// Block = 256 threads (4 waves) handles (b, 4 consecutive queries); each wave
// owns ONE query, single pass. Candidates live in 32 NAMED scalar VGPRs
// (c00..c31) — no array, nothing runtime-indexed, so no scratch demotion
// (R3/R4 had cand[] demoted to scratch: VGPR_Count=52 < 64 live values).
// Per round: (key,slot) pairwise tree (strict <, slots-contiguous pairing ->
// ties pick lower slot = lower j), then ONE packed u64 butterfly on
// (key<<12)|(slot<<6)|lane -> global min with smallest-j tie-break.
// Exact (d, j) lexicographic semantics — matches lax.top_k.
template<int C>
__global__ __launch_bounds__(256, 4) void knn_kernel(const float* __restrict__ x,
                                                     const float* __restrict__ sq,
                                                     int* __restrict__ idx) {
    const int QT = 4;
    __shared__ unsigned dl[QT][NN];   // 32 KB of monotone keys
    __shared__ float xq[QT][C];
    __shared__ float sqq[QT];
    int blk = blockIdx.x;
    int b = blk / (NN / QT);
    int q0 = (blk - b * (NN / QT)) * QT;
    int t = threadIdx.x;
    int lane = t & 63, wid = t >> 6;

    const float* xb = x + (size_t)b * C * NN;
    for (int e = t; e < QT * C; e += 256) {
        int q = e / C, c = e - q * C;
        xq[q][c] = xb[(size_t)c * NN + q0 + q];
    }
    if (t < QT) sqq[t] = sq[b * NN + q0 + t];
    __syncthreads();

    float acc[QT][8];
    #pragma unroll
    for (int q = 0; q < QT; ++q)
        #pragma unroll
        for (int s = 0; s < 8; ++s) acc[q][s] = 0.f;

    for (int c = 0; c < C; ++c) {
        float xj[8];
        #pragma unroll
        for (int s = 0; s < 8; ++s) xj[s] = xb[(size_t)c * NN + t + s * 256];
        #pragma unroll
        for (int q = 0; q < QT; ++q) {
            float xqc = xq[q][c];
            #pragma unroll
            for (int s = 0; s < 8; ++s) acc[q][s] = fmaf(xqc, xj[s], acc[q][s]);
        }
    }
    float sqj[8];
    #pragma unroll
    for (int s = 0; s < 8; ++s) sqj[s] = sq[b * NN + t + s * 256];

    // d = sq_i + sq_j - 2*inner (same expression as R2/R3/R4 — values
    // bit-identical), then monotone u32 key (validated in R4: passed).
    #pragma unroll
    for (int q = 0; q < QT; ++q) {
        float sqi = sqq[q];
        #pragma unroll
        for (int s = 0; s < 8; ++s) {
            float d = sqi + sqj[s] - 2.f * acc[q][s];
            unsigned u = __float_as_uint(d);
            dl[q][s * 256 + t] = u ^ ((unsigned)((int)u >> 31) | 0x80000000u);
        }
    }
    __syncthreads();

    // wave wid owns query q0+wid; lane holds candidates j = X*64 + lane
    const unsigned* dp = dl[wid];
    unsigned c00 = dp[lane +  0 * 64], c01 = dp[lane +  1 * 64];
    unsigned c02 = dp[lane +  2 * 64], c03 = dp[lane +  3 * 64];
    unsigned c04 = dp[lane +  4 * 64], c05 = dp[lane +  5 * 64];
    unsigned c06 = dp[lane +  6 * 64], c07 = dp[lane +  7 * 64];
    unsigned c08 = dp[lane +  8 * 64], c09 = dp[lane +  9 * 64];
    unsigned c10 = dp[lane + 10 * 64], c11 = dp[lane + 11 * 64];
    unsigned c12 = dp[lane + 12 * 64], c13 = dp[lane + 13 * 64];
    unsigned c14 = dp[lane + 14 * 64], c15 = dp[lane + 15 * 64];
    unsigned c16 = dp[lane + 16 * 64], c17 = dp[lane + 17 * 64];
    unsigned c18 = dp[lane + 18 * 64], c19 = dp[lane + 19 * 64];
    unsigned c20 = dp[lane + 20 * 64], c21 = dp[lane + 21 * 64];
    unsigned c22 = dp[lane + 22 * 64], c23 = dp[lane + 23 * 64];
    unsigned c24 = dp[lane + 24 * 64], c25 = dp[lane + 25 * 64];
    unsigned c26 = dp[lane + 26 * 64], c27 = dp[lane + 27 * 64];
    unsigned c28 = dp[lane + 28 * 64], c29 = dp[lane + 29 * 64];
    unsigned c30 = dp[lane + 30 * 64], c31 = dp[lane + 31 * 64];

    int* orow = idx + (size_t)(b * NN + q0 + wid) * KK;
    #pragma unroll 1
    for (int r = 0; r < KK; ++r) {
        unsigned k16[16]; int s16[16];
#define L1N(i, A, B) { bool w = (B) < (A); k16[i] = w ? (B) : (A); s16[i] = w ? 2*(i)+1 : 2*(i); }
        L1N(0, c00, c01)  L1N(1, c02, c03)  L1N(2, c04, c05)  L1N(3, c06, c07)
        L1N(4, c08, c09)  L1N(5, c10, c11)  L1N(6, c12, c13)  L1N(7, c14, c15)
        L1N(8, c16, c17)  L1N(9, c18, c19)  L1N(10, c20, c21) L1N(11, c22, c23)
        L1N(12, c24, c25) L1N(13, c26, c27) L1N(14, c28, c29) L1N(15, c30, c31)
#undef L1N
        unsigned k8[8]; int s8[8];
        #pragma unroll
        for (int i = 0; i < 8; ++i) {
            bool w = k16[2 * i + 1] < k16[2 * i];
            k8[i] = w ? k16[2 * i + 1] : k16[2 * i];
            s8[i] = w ? s16[2 * i + 1] : s16[2 * i];
        }
        unsigned k4[4]; int s4[4];
        #pragma unroll
        for (int i = 0; i < 4; ++i) {
            bool w = k8[2 * i + 1] < k8[2 * i];
            k4[i] = w ? k8[2 * i + 1] : k8[2 * i];
            s4[i] = w ? s8[2 * i + 1] : s8[2 * i];
        }
        unsigned k2[2]; int s2[2];
        #pragma unroll
        for (int i = 0; i < 2; ++i) {
            bool w = k4[2 * i + 1] < k4[2 * i];
            k2[i] = w ? k4[2 * i + 1] : k4[2 * i];
            s2[i] = w ? s4[2 * i + 1] : s4[2 * i];
        }
        bool w0 = k2[1] < k2[0];
        unsigned vk = w0 ? k2[1] : k2[0];
        int vs = w0 ? s2[1] : s2[0];

        // packed (key | slot | lane): global u64 min = (d, j) lexicographic min
        unsigned long long pk =
            ((unsigned long long)vk << 12) | (unsigned)((vs << 6) | lane);
        #pragma unroll
        for (int off = 32; off >= 1; off >>= 1) {
            unsigned long long o = __shfl_xor(pk, off);
            pk = o < pk ? o : pk;
        }
        int j = (int)((unsigned)pk & 0xFFFu);   // == winning global index
        if (lane == 0) orow[r] = j;
        int sw = j >> 6;
        if ((j & 63) == lane) {
#define INV(i, R) R = (sw == (i)) ? 0xFFFFFFFFu : R;
            INV(0, c00)  INV(1, c01)  INV(2, c02)  INV(3, c03)
            INV(4, c04)  INV(5, c05)  INV(6, c06)  INV(7, c07)
            INV(8, c08)  INV(9, c09)  INV(10, c10) INV(11, c11)
            INV(12, c12) INV(13, c13) INV(14, c14) INV(15, c15)
            INV(16, c16) INV(17, c17) INV(18, c18) INV(19, c19)
            INV(20, c20) INV(21, c21) INV(22, c22) INV(23, c23)
            INV(24, c24) INV(25, c25) INV(26, c26) INV(27, c27)
            INV(28, c28) INV(29, c29) INV(30, c30) INV(31, c31)
#undef INV
        }
    }
}

// ---------------- p/t: p = Wn·x, t = (Wc-Wn)·x ----------------
template<int C, int OT>
__global__ __launch_bounds__(256) void pt_kernel(const float* __restrict__ x,
                                                 const float* __restrict__ W,
                                                 float* __restrict__ p,
                                                 float* __restrict__ tt,
                                                 int O) {
    const int NB = NN / 256;
    int blk = blockIdx.x;
    int nb = blk % NB;
    int rest = blk / NB;
    int nob = O / OT;
    int ob = rest % nob;
    int b = rest / nob;
    int t = threadIdx.x;
    int n = nb * 256 + t;
    __shared__ float wn[OT][C], wd[OT][C];
    for (int e = t; e < OT * C; e += 256) {
        int o = e / C, c = e - o * C;
        float a = W[(size_t)(ob * OT + o) * (2 * C) + c];
        float b2 = W[(size_t)(ob * OT + o) * (2 * C) + C + c];
        wn[o][c] = a;
        wd[o][c] = b2 - a;
    }
    __syncthreads();
    float ap[OT], at[OT];
    #pragma unroll
    for (int o = 0; o < OT; ++o) { ap[o] = 0.f; at[o] = 0.f; }
    const float* xb = x + (size_t)b * C * NN + n;
    for (int c = 0; c < C; ++c) {
        float xv = xb[(size_t)c * NN];
        #pragma unroll
        for (int o = 0; o < OT; ++o) {
            ap[o] = fmaf(wn[o][c], xv, ap[o]);
            at[o] = fmaf(wd[o][c], xv, at[o]);
        }
    }
    size_t base = ((size_t)b * O + ob * OT) * NN + n;
    #pragma unroll
    for (int o = 0; o < OT; ++o) {
        p[base + (size_t)o * NN] = ap[o];
        tt[base + (size_t)o * NN] = at[o];
    }
}

// ---------------- edge max: out[b,o,i] = max_k lrelu(scale*(p[j]+t_i)+beta) ----------------
__global__ __launch_bounds__(256) void edge_kernel(const float* __restrict__ p,
                                                   const float* __restrict__ tt,
                                                   const int* __restrict__ idx,
                                                   const float* __restrict__ g,
                                                   const float* __restrict__ be,
                                                   float* __restrict__ out, int O) {
    int b = blockIdx.x / O, o = blockIdx.x - b * O;
    __shared__ float pl[NN];
    const float* pr = p + ((size_t)b * O + o) * NN;
    for (int e = threadIdx.x * 4; e < NN; e += 1024)
        *(float4*)&pl[e] = *(const float4*)&pr[e];
    __syncthreads();
    float scale = g[o] / sqrtf(1.f + 1e-5f);
    float beta = be[o];
    const float* tr = tt + ((size_t)b * O + o) * NN;
    float* orow = out + ((size_t)b * O + o) * NN;
    for (int i = threadIdx.x; i < NN; i += 256) {
        float ti = tr[i];
        const int4* ir4 = (const int4*)(idx + (size_t)(b * NN + i) * KK);
        int4 w0 = ir4[0], w1 = ir4[1], w2 = ir4[2], w3 = ir4[3], w4 = ir4[4];
        float m = -__builtin_inff();
        int js[20] = {w0.x, w0.y, w0.z, w0.w, w1.x, w1.y, w1.z, w1.w,
                      w2.x, w2.y, w2.z, w2.w, w3.x, w3.y, w3.z, w3.w,
                      w4.x, w4.y, w4.z, w4.w};
        #pragma unroll
        for (int k = 0; k < KK; ++k) {
            float y = pl[js[k]] + ti;
            m = fmaxf(m, lrelu(fmaf(scale, y, beta)));
        }
        orow[i] = m;
    }
}

// ---------------- transpose W5 [1024][256] -> W5T [256][1024] ----------------
__global__ __launch_bounds__(256) void transpose_kernel(const float* __restrict__ W,
                                                        float* __restrict__ WT) {
    __shared__ float tile[32][33];
    int c0 = blockIdx.x * 32, o0 = blockIdx.y * 32;
    int tx = threadIdx.x, ty = threadIdx.y;   // 32 x 8
    #pragma unroll
    for (int i = 0; i < 32; i += 8)
        tile[ty + i][tx] = W[(size_t)(o0 + ty + i) * 256 + c0 + tx];
    __syncthreads();
    #pragma unroll
    for (int i = 0; i < 32; i += 8)
        WT[(size_t)(c0 + ty + i) * 1024 + o0 + tx] = tile[tx][ty + i];
}

// ---------------- final: register-tiled GEMM + fused lrelu + max over n ----------------
__global__ __launch_bounds__(256) void final_kernel(const float* __restrict__ x4,
                                                    const float* __restrict__ W5T,
                                                    const float* __restrict__ g,
                                                    const float* __restrict__ be,
                                                    float* __restrict__ partial) {
    const int CC = 256;
    __shared__ float xs[64][64];
    __shared__ float ws[64][64];
    int blk = blockIdx.x;
    int nb = blk & 31;
    int ob = (blk >> 5) & 15;
    int b  = blk >> 9;
    int t = threadIdx.x;
    int tn = t & 15, to = t >> 4;

    float acc[4][4];
    #pragma unroll
    for (int i = 0; i < 4; ++i)
        #pragma unroll
        for (int j = 0; j < 4; ++j) acc[i][j] = 0.f;

    for (int c0 = 0; c0 < CC; c0 += 64) {
        __syncthreads();
        #pragma unroll
        for (int e = t * 4; e < 64 * 64; e += 1024) {
            int c = e >> 6, n = e & 63;
            *(float4*)&xs[c][n] =
                *(const float4*)&x4[((size_t)b * CC + c0 + c) * NN + nb * 64 + n];
        }
        #pragma unroll
        for (int e = t * 4; e < 64 * 64; e += 1024) {
            int c = e >> 6, o = e & 63;
            *(float4*)&ws[c][o] =
                *(const float4*)&W5T[(size_t)(c0 + c) * 1024 + ob * 64 + o];
        }
        __syncthreads();
        for (int c = 0; c < 64; ++c) {
            float4 xv = *(float4*)&xs[c][tn * 4];
            float4 wv = *(float4*)&ws[c][to * 4];
            acc[0][0] = fmaf(wv.x, xv.x, acc[0][0]);
            acc[0][1] = fmaf(wv.x, xv.y, acc[0][1]);
            acc[0][2] = fmaf(wv.x, xv.z, acc[0][2]);
            acc[0][3] = fmaf(wv.x, xv.w, acc[0][3]);
            acc[1][0] = fmaf(wv.y, xv.x, acc[1][0]);
            acc[1][1] = fmaf(wv.y, xv.y, acc[1][1]);
            acc[1][2] = fmaf(wv.y, xv.z, acc[1][2]);
            acc[1][3] = fmaf(wv.y, xv.w, acc[1][3]);
            acc[2][0] = fmaf(wv.z, xv.x, acc[2][0]);
            acc[2][1] = fmaf(wv.z, xv.y, acc[2][1]);
            acc[2][2] = fmaf(wv.z, xv.z, acc[2][2]);
            acc[2][3] = fmaf(wv.z, xv.w, acc[2][3]);
            acc[3][0] = fmaf(wv.w, xv.x, acc[3][0]);
            acc[3][1] = fmaf(wv.w, xv.y, acc[3][1]);
            acc[3][2] = fmaf(wv.w, xv.z, acc[3][2]);
            acc[3][3] = fmaf(wv.w, xv.w, acc[3][3]);
        }
    }

    float rs = 1.f / sqrtf(1.f + 1e-5f);
    #pragma unroll
    for (int i = 0; i < 4; ++i) {
        int o = ob * 64 + to * 4 + i;
        float scale = g[o] * rs, beta = be[o];
        float m = -__builtin_inff();
        #pragma unroll
        for (int j = 0; j < 4; ++j)
            m = fmaxf(m, lrelu(fmaf(scale, acc[i][j], beta)));
        #pragma unroll
        for (int off = 8; off >= 1; off >>= 1)
            m = fmaxf(m, __shfl_xor(m, off));
        if (tn == 0)
            partial[(size_t)(nb * BB + b) * 1024 + o] = m;
    }
}

__global__ __launch_bounds__(256) void reduce32_kernel(const float* __restrict__ partial,
                                                       float* __restrict__ out) {
    int i = blockIdx.x * 256 + threadIdx.x;
    if (i >= BB * 1024) return;
    int b = i >> 10, o = i & 1023;
    float m = -__builtin_inff();
    #pragma unroll
    for (int nb = 0; nb < 32; ++nb)
        m = fmaxf(m, partial[(size_t)(nb * BB + b) * 1024 + o]);
    out[i] = m;
}

extern "C" void kernel_launch(void* const* d_in, const int* in_sizes, int n_in,
                              void* d_out, int out_size, void* d_ws, size_t ws_size,
                              hipStream_t stream) {
    const float* x  = (const float*)d_in[0];
    const float* W1 = (const float*)d_in[1];
    const float* g1 = (const float*)d_in[2];
    const float* b1 = (const float*)d_in[3];
    const float* W2 = (const float*)d_in[4];
    const float* g2 = (const float*)d_in[5];
    const float* b2 = (const float*)d_in[6];
    const float* W3 = (const float*)d_in[7];
    const float* g3 = (const float*)d_in[8];
    const float* b3 = (const float*)d_in[9];
    const float* W4 = (const float*)d_in[10];
    const float* g4 = (const float*)d_in[11];
    const float* b4 = (const float*)d_in[12];
    const float* W5 = (const float*)d_in[13];
    const float* g5 = (const float*)d_in[14];
    const float* b5 = (const float*)d_in[15];

    float* ws = (float*)d_ws;
    float* sq      = ws;                       // 8192
    int*   idx     = (int*)(ws + 8192);        // 163840 ints
    float* x1      = ws + 8192 + 163840;       // 524288
    float* x2      = x1 + 524288;              // 524288
    float* x3      = x2 + 524288;              // 1048576
    float* x4      = x3 + 1048576;             // 2097152
    float* p       = x4 + 2097152;             // 2097152
    float* tt      = p + 2097152;              // 2097152
    float* W5T     = p;                        // reuse (dead after layer 4)
    float* partial = tt;                       // reuse

    dim3 blk(256);

    // ---- layer 1: C=3, O=64 ----
    sq_kernel<3><<<32, blk, 0, stream>>>(x, sq);
    knn_kernel<3><<<BB * (NN / 4), blk, 0, stream>>>(x, sq, idx);
    pt_kernel<3, 16><<<BB * (64 / 16) * (NN / 256), blk, 0, stream>>>(x, W1, p, tt, 64);
    edge_kernel<<<BB * 64, blk, 0, stream>>>(p, tt, idx, g1, b1, x1, 64);

    // ---- layer 2: C=64, O=64 ----
    sq_kernel<64><<<32, blk, 0, stream>>>(x1, sq);
    knn_kernel<64><<<BB * (NN / 4), blk, 0, stream>>>(x1, sq, idx);
    pt_kernel<64, 16><<<BB * (64 / 16) * (NN / 256), blk, 0, stream>>>(x1, W2, p, tt, 64);
    edge_kernel<<<BB * 64, blk, 0, stream>>>(p, tt, idx, g2, b2, x2, 64);

    // ---- layer 3: C=64, O=128 ----
    sq_kernel<64><<<32, blk, 0, stream>>>(x2, sq);
    knn_kernel<64><<<BB * (NN / 4), blk, 0, stream>>>(x2, sq, idx);
    pt_kernel<64, 16><<<BB * (128 / 16) * (NN / 256), blk, 0, stream>>>(x2, W3, p, tt, 128);
    edge_kernel<<<BB * 128, blk, 0, stream>>>(p, tt, idx, g3, b3, x3, 128);

    // ---- layer 4: C=128, O=256 ----
    sq_kernel<128><<<32, blk, 0, stream>>>(x3, sq);
    knn_kernel<128><<<BB * (NN / 4), blk, 0, stream>>>(x3, sq, idx);
    pt_kernel<128, 16><<<BB * (256 / 16) * (NN / 256), blk, 0, stream>>>(x3, W4, p, tt, 256);
    edge_kernel<<<BB * 256, blk, 0, stream>>>(p, tt, idx, g4, b4, x4, 256);

    // ---- layer 5: C=256, O=1024, fused max over n ----
    transpose_kernel<<<dim3(8, 32), dim3(32, 8), 0, stream>>>(W5, W5T);
    final_kernel<<<BB * 16 * 32, blk, 0, stream>>>(x4, W5T, g5, b5, partial);
    reduce32_kernel<<<16, blk, 0, stream>>>(partial, (float*)d_out);
}

// Round 7
// 636.679 us; speedup vs baseline: 1.6549x; 1.3579x over previous
//
#include <hip/hip_runtime.h>
#include <math.h>

#define BB 4
#define NN 2048
#define KK 20

static __device__ __forceinline__ float lrelu(float z) {
    return z >= 0.f ? z : 0.2f * z;
}

// DPP-based full-wave u32 min, result broadcast to all lanes via readlane 63.
// Classic gfx9 sequence: row_shr 1,2,4,8 accumulate, row_bcast:15, row_bcast:31.
// OOB source lanes keep `old` = 0xFFFFFFFF (identity for min).
template<int CTRL>
static __device__ __forceinline__ unsigned dpp_min_step(unsigned v) {
    unsigned t = (unsigned)__builtin_amdgcn_update_dpp(
        (int)0xFFFFFFFFu, (int)v, CTRL, 0xF, 0xF, false);
    return v < t ? v : t;
}
static __device__ __forceinline__ unsigned wave_min_bcast(unsigned v) {
    v = dpp_min_step<0x111>(v);   // row_shr:1
    v = dpp_min_step<0x112>(v);   // row_shr:2
    v = dpp_min_step<0x114>(v);   // row_shr:4
    v = dpp_min_step<0x118>(v);   // row_shr:8
    v = dpp_min_step<0x142>(v);   // row_bcast:15
    v = dpp_min_step<0x143>(v);   // row_bcast:31  -> lane 63 has global min
    return (unsigned)__builtin_amdgcn_readlane((int)v, 63);
}

// ---------------- sq: per-point squared norm ----------------
template<int C>
__global__ __launch_bounds__(256) void sq_kernel(const float* __restrict__ x,
                                                 float* __restrict__ sq) {
    int i = blockIdx.x * 256 + threadIdx.x;
    if (i >= BB * NN) return;
    int b = i / NN, n = i - b * NN;
    const float* xb = x + (size_t)b * C * NN + n;
    float s = 0.f;
    #pragma unroll
    for (int c = 0; c < C; ++c) {
        float v = xb[(size_t)c * NN];
        s = fmaf(v, v, s);
    }
    sq[i] = s;
}

// ---------------- knn: top-20 smallest distance indices ----------------
// Block = 256 threads (4 waves) = (b, 4 queries); wave owns ONE query.
// Keys (monotone u32 of distance) live ONLY in LDS: lane owns contiguous
// j-range [32*lane, 32*lane+31], stored quad-XOR-swizzled so the per-round
// 8x ds_read_b128 re-read is conflict-free. NO loop-carried register arrays
// (R3/R4/R6 all stuck at VGPR=52 => demoted state), NO __shfl butterflies
// (each is a ds_bpermute chain; 12 serial stages/round was the latency wall).
// Per round: pair-tree (key,slot) over 32 (ties->left=smaller j), DPP key-min,
// DPP min over j among key==g, winner lane rewrites its own LDS slot to INF
// (no barrier: each lane owns its chunk exclusively).
// Exact (d, j) lexicographic semantics — matches lax.top_k.
template<int C>
__global__ __launch_bounds__(256, 4) void knn_kernel(const float* __restrict__ x,
                                                     const float* __restrict__ sq,
                                                     int* __restrict__ idx) {
    const int QT = 4;
    __shared__ unsigned dl[QT][NN];   // 32 KB swizzled keys
    __shared__ float xq[QT][C];
    __shared__ float sqq[QT];
    int blk = blockIdx.x;
    int b = blk / (NN / QT);
    int q0 = (blk - b * (NN / QT)) * QT;
    int t = threadIdx.x;
    int lane = t & 63, wid = t >> 6;

    const float* xb = x + (size_t)b * C * NN;
    for (int e = t; e < QT * C; e += 256) {
        int q = e / C, c = e - q * C;
        xq[q][c] = xb[(size_t)c * NN + q0 + q];
    }
    if (t < QT) sqq[t] = sq[b * NN + q0 + t];
    __syncthreads();

    float acc[QT][8];
    #pragma unroll
    for (int q = 0; q < QT; ++q)
        #pragma unroll
        for (int s = 0; s < 8; ++s) acc[q][s] = 0.f;

    for (int c = 0; c < C; ++c) {
        float xj[8];
        #pragma unroll
        for (int s = 0; s < 8; ++s) xj[s] = xb[(size_t)c * NN + t + s * 256];
        #pragma unroll
        for (int q = 0; q < QT; ++q) {
            float xqc = xq[q][c];
            #pragma unroll
            for (int s = 0; s < 8; ++s) acc[q][s] = fmaf(xqc, xj[s], acc[q][s]);
        }
    }
    float sqj[8];
    #pragma unroll
    for (int s = 0; s < 8; ++s) sqj[s] = sq[b * NN + t + s * 256];

    // d = sq_i + sq_j - 2*inner (bit-identical expression to R2..R6), monotone
    // u32 key, stored at swizzled word W(j) = (j&~31) | ((((j>>2)^(j>>5))&7)<<2) | (j&3).
    #pragma unroll
    for (int q = 0; q < QT; ++q) {
        float sqi = sqq[q];
        #pragma unroll
        for (int s = 0; s < 8; ++s) {
            float d = sqi + sqj[s] - 2.f * acc[q][s];
            unsigned u = __float_as_uint(d);
            unsigned key = u ^ ((unsigned)((int)u >> 31) | 0x80000000u);
            int j = s * 256 + t;
            int w = (j & ~31) | ((((j >> 2) ^ (j >> 5)) & 7) << 2) | (j & 3);
            dl[q][w] = key;
        }
    }
    __syncthreads();

    unsigned* dq = &dl[wid][0];
    int r7 = lane & 7;
    int lanebase = lane << 5;
    // chunk c holds logical slots 4c..4c+3 at word offset lanebase + ((c^r7)<<2)
    const uint4* cp0 = (const uint4*)(dq + lanebase + ((0 ^ r7) << 2));
    const uint4* cp1 = (const uint4*)(dq + lanebase + ((1 ^ r7) << 2));
    const uint4* cp2 = (const uint4*)(dq + lanebase + ((2 ^ r7) << 2));
    const uint4* cp3 = (const uint4*)(dq + lanebase + ((3 ^ r7) << 2));
    const uint4* cp4 = (const uint4*)(dq + lanebase + ((4 ^ r7) << 2));
    const uint4* cp5 = (const uint4*)(dq + lanebase + ((5 ^ r7) << 2));
    const uint4* cp6 = (const uint4*)(dq + lanebase + ((6 ^ r7) << 2));
    const uint4* cp7 = (const uint4*)(dq + lanebase + ((7 ^ r7) << 2));

    int* orow = idx + (size_t)(b * NN + q0 + wid) * KK;
    #pragma unroll 1
    for (int rr = 0; rr < KK; ++rr) {
        uint4 v0 = *cp0, v1 = *cp1, v2 = *cp2, v3 = *cp3;
        uint4 v4 = *cp4, v5 = *cp5, v6 = *cp6, v7 = *cp7;
        // per-chunk (key, slot): pairs are j-ascending; strict < keeps left on tie
        unsigned ck[8]; int cs[8];
#define CHUNK(i, V) {                                                   \
        unsigned kA = (V.y < V.x) ? V.y : V.x;                          \
        int      sA = 4*(i) + ((V.y < V.x) ? 1 : 0);                    \
        unsigned kB = (V.w < V.z) ? V.w : V.z;                          \
        int      sB = 4*(i) + 2 + ((V.w < V.z) ? 1 : 0);                \
        bool w2 = kB < kA;                                              \
        ck[i] = w2 ? kB : kA; cs[i] = w2 ? sB : sA; }
        CHUNK(0, v0) CHUNK(1, v1) CHUNK(2, v2) CHUNK(3, v3)
        CHUNK(4, v4) CHUNK(5, v5) CHUNK(6, v6) CHUNK(7, v7)
#undef CHUNK
        unsigned k01 = ck[1] < ck[0] ? ck[1] : ck[0];
        int      s01 = ck[1] < ck[0] ? cs[1] : cs[0];
        unsigned k23 = ck[3] < ck[2] ? ck[3] : ck[2];
        int      s23 = ck[3] < ck[2] ? cs[3] : cs[2];
        unsigned k45 = ck[5] < ck[4] ? ck[5] : ck[4];
        int      s45 = ck[5] < ck[4] ? cs[5] : cs[4];
        unsigned k67 = ck[7] < ck[6] ? ck[7] : ck[6];
        int      s67 = ck[7] < ck[6] ? cs[7] : cs[6];
        unsigned k03 = k23 < k01 ? k23 : k01;
        int      s03 = k23 < k01 ? s23 : s01;
        unsigned k47 = k67 < k45 ? k67 : k45;
        int      s47 = k67 < k45 ? s67 : s45;
        bool wf = k47 < k03;
        unsigned kf = wf ? k47 : k03;
        int      sf = wf ? s47 : s03;

        unsigned g = wave_min_bcast(kf);                       // uniform
        unsigned encl = (kf == g) ? (unsigned)(lanebase + sf) : 0xFFFFFFFFu;
        unsigned j = wave_min_bcast(encl);                     // uniform = winner j
        if (lane == 0) orow[rr] = (int)j;
        if ((int)(j >> 5) == lane) {                           // owner invalidates
            int lo = (int)j & 31;
            dq[lanebase + (((lo >> 2) ^ r7) << 2) + (lo & 3)] = 0xFFFFFFFFu;
        }
    }
}

// ---------------- p/t: p = Wn·x, t = (Wc-Wn)·x ----------------
template<int C, int OT>
__global__ __launch_bounds__(256) void pt_kernel(const float* __restrict__ x,
                                                 const float* __restrict__ W,
                                                 float* __restrict__ p,
                                                 float* __restrict__ tt,
                                                 int O) {
    const int NB = NN / 256;
    int blk = blockIdx.x;
    int nb = blk % NB;
    int rest = blk / NB;
    int nob = O / OT;
    int ob = rest % nob;
    int b = rest / nob;
    int t = threadIdx.x;
    int n = nb * 256 + t;
    __shared__ float wn[OT][C], wd[OT][C];
    for (int e = t; e < OT * C; e += 256) {
        int o = e / C, c = e - o * C;
        float a = W[(size_t)(ob * OT + o) * (2 * C) + c];
        float b2 = W[(size_t)(ob * OT + o) * (2 * C) + C + c];
        wn[o][c] = a;
        wd[o][c] = b2 - a;
    }
    __syncthreads();
    float ap[OT], at[OT];
    #pragma unroll
    for (int o = 0; o < OT; ++o) { ap[o] = 0.f; at[o] = 0.f; }
    const float* xb = x + (size_t)b * C * NN + n;
    for (int c = 0; c < C; ++c) {
        float xv = xb[(size_t)c * NN];
        #pragma unroll
        for (int o = 0; o < OT; ++o) {
            ap[o] = fmaf(wn[o][c], xv, ap[o]);
            at[o] = fmaf(wd[o][c], xv, at[o]);
        }
    }
    size_t base = ((size_t)b * O + ob * OT) * NN + n;
    #pragma unroll
    for (int o = 0; o < OT; ++o) {
        p[base + (size_t)o * NN] = ap[o];
        tt[base + (size_t)o * NN] = at[o];
    }
}

// ---------------- edge max: out[b,o,i] = max_k lrelu(scale*(p[j]+t_i)+beta) ----------------
__global__ __launch_bounds__(256) void edge_kernel(const float* __restrict__ p,
                                                   const float* __restrict__ tt,
                                                   const int* __restrict__ idx,
                                                   const float* __restrict__ g,
                                                   const float* __restrict__ be,
                                                   float* __restrict__ out, int O) {
    int b = blockIdx.x / O, o = blockIdx.x - b * O;
    __shared__ float pl[NN];
    const float* pr = p + ((size_t)b * O + o) * NN;
    for (int e = threadIdx.x * 4; e < NN; e += 1024)
        *(float4*)&pl[e] = *(const float4*)&pr[e];
    __syncthreads();
    float scale = g[o] / sqrtf(1.f + 1e-5f);
    float beta = be[o];
    const float* tr = tt + ((size_t)b * O + o) * NN;
    float* orow = out + ((size_t)b * O + o) * NN;
    for (int i = threadIdx.x; i < NN; i += 256) {
        float ti = tr[i];
        const int4* ir4 = (const int4*)(idx + (size_t)(b * NN + i) * KK);
        int4 w0 = ir4[0], w1 = ir4[1], w2 = ir4[2], w3 = ir4[3], w4 = ir4[4];
        float m = -__builtin_inff();
        int js[20] = {w0.x, w0.y, w0.z, w0.w, w1.x, w1.y, w1.z, w1.w,
                      w2.x, w2.y, w2.z, w2.w, w3.x, w3.y, w3.z, w3.w,
                      w4.x, w4.y, w4.z, w4.w};
        #pragma unroll
        for (int k = 0; k < KK; ++k) {
            float y = pl[js[k]] + ti;
            m = fmaxf(m, lrelu(fmaf(scale, y, beta)));
        }
        orow[i] = m;
    }
}

// ---------------- transpose W5 [1024][256] -> W5T [256][1024] ----------------
__global__ __launch_bounds__(256) void transpose_kernel(const float* __restrict__ W,
                                                        float* __restrict__ WT) {
    __shared__ float tile[32][33];
    int c0 = blockIdx.x * 32, o0 = blockIdx.y * 32;
    int tx = threadIdx.x, ty = threadIdx.y;   // 32 x 8
    #pragma unroll
    for (int i = 0; i < 32; i += 8)
        tile[ty + i][tx] = W[(size_t)(o0 + ty + i) * 256 + c0 + tx];
    __syncthreads();
    #pragma unroll
    for (int i = 0; i < 32; i += 8)
        WT[(size_t)(c0 + ty + i) * 1024 + o0 + tx] = tile[tx][ty + i];
}

// ---------------- final: register-tiled GEMM + fused lrelu + max over n ----------------
__global__ __launch_bounds__(256) void final_kernel(const float* __restrict__ x4,
                                                    const float* __restrict__ W5T,
                                                    const float* __restrict__ g,
                                                    const float* __restrict__ be,
                                                    float* __restrict__ partial) {
    const int CC = 256;
    __shared__ float xs[64][64];
    __shared__ float ws[64][64];
    int blk = blockIdx.x;
    int nb = blk & 31;
    int ob = (blk >> 5) & 15;
    int b  = blk >> 9;
    int t = threadIdx.x;
    int tn = t & 15, to = t >> 4;

    float acc[4][4];
    #pragma unroll
    for (int i = 0; i < 4; ++i)
        #pragma unroll
        for (int j = 0; j < 4; ++j) acc[i][j] = 0.f;

    for (int c0 = 0; c0 < CC; c0 += 64) {
        __syncthreads();
        #pragma unroll
        for (int e = t * 4; e < 64 * 64; e += 1024) {
            int c = e >> 6, n = e & 63;
            *(float4*)&xs[c][n] =
                *(const float4*)&x4[((size_t)b * CC + c0 + c) * NN + nb * 64 + n];
        }
        #pragma unroll
        for (int e = t * 4; e < 64 * 64; e += 1024) {
            int c = e >> 6, o = e & 63;
            *(float4*)&ws[c][o] =
                *(const float4*)&W5T[(size_t)(c0 + c) * 1024 + ob * 64 + o];
        }
        __syncthreads();
        for (int c = 0; c < 64; ++c) {
            float4 xv = *(float4*)&xs[c][tn * 4];
            float4 wv = *(float4*)&ws[c][to * 4];
            acc[0][0] = fmaf(wv.x, xv.x, acc[0][0]);
            acc[0][1] = fmaf(wv.x, xv.y, acc[0][1]);
            acc[0][2] = fmaf(wv.x, xv.z, acc[0][2]);
            acc[0][3] = fmaf(wv.x, xv.w, acc[0][3]);
            acc[1][0] = fmaf(wv.y, xv.x, acc[1][0]);
            acc[1][1] = fmaf(wv.y, xv.y, acc[1][1]);
            acc[1][2] = fmaf(wv.y, xv.z, acc[1][2]);
            acc[1][3] = fmaf(wv.y, xv.w, acc[1][3]);
            acc[2][0] = fmaf(wv.z, xv.x, acc[2][0]);
            acc[2][1] = fmaf(wv.z, xv.y, acc[2][1]);
            acc[2][2] = fmaf(wv.z, xv.z, acc[2][2]);
            acc[2][3] = fmaf(wv.z, xv.w, acc[2][3]);
            acc[3][0] = fmaf(wv.w, xv.x, acc[3][0]);
            acc[3][1] = fmaf(wv.w, xv.y, acc[3][1]);
            acc[3][2] = fmaf(wv.w, xv.z, acc[3][2]);
            acc[3][3] = fmaf(wv.w, xv.w, acc[3][3]);
        }
    }

    float rs = 1.f / sqrtf(1.f + 1e-5f);
    #pragma unroll
    for (int i = 0; i < 4; ++i) {
        int o = ob * 64 + to * 4 + i;
        float scale = g[o] * rs, beta = be[o];
        float m = -__builtin_inff();
        #pragma unroll
        for (int j = 0; j < 4; ++j)
            m = fmaxf(m, lrelu(fmaf(scale, acc[i][j], beta)));
        #pragma unroll
        for (int off = 8; off >= 1; off >>= 1)
            m = fmaxf(m, __shfl_xor(m, off));
        if (tn == 0)
            partial[(size_t)(nb * BB + b) * 1024 + o] = m;
    }
}

__global__ __launch_bounds__(256) void reduce32_kernel(const float* __restrict__ partial,
                                                       float* __restrict__ out) {
    int i = blockIdx.x * 256 + threadIdx.x;
    if (i >= BB * 1024) return;
    int b = i >> 10, o = i & 1023;
    float m = -__builtin_inff();
    #pragma unroll
    for (int nb = 0; nb < 32; ++nb)
        m = fmaxf(m, partial[(size_t)(nb * BB + b) * 1024 + o]);
    out[i] = m;
}

extern "C" void kernel_launch(void* const* d_in, const int* in_sizes, int n_in,
                              void* d_out, int out_size, void* d_ws, size_t ws_size,
                              hipStream_t stream) {
    const float* x  = (const float*)d_in[0];
    const float* W1 = (const float*)d_in[1];
    const float* g1 = (const float*)d_in[2];
    const float* b1 = (const float*)d_in[3];
    const float* W2 = (const float*)d_in[4];
    const float* g2 = (const float*)d_in[5];
    const float* b2 = (const float*)d_in[6];
    const float* W3 = (const float*)d_in[7];
    const float* g3 = (const float*)d_in[8];
    const float* b3 = (const float*)d_in[9];
    const float* W4 = (const float*)d_in[10];
    const float* g4 = (const float*)d_in[11];
    const float* b4 = (const float*)d_in[12];
    const float* W5 = (const float*)d_in[13];
    const float* g5 = (const float*)d_in[14];
    const float* b5 = (const float*)d_in[15];

    float* ws = (float*)d_ws;
    float* sq      = ws;                       // 8192
    int*   idx     = (int*)(ws + 8192);        // 163840 ints
    float* x1      = ws + 8192 + 163840;       // 524288
    float* x2      = x1 + 524288;              // 524288
    float* x3      = x2 + 524288;              // 1048576
    float* x4      = x3 + 1048576;             // 2097152
    float* p       = x4 + 2097152;             // 2097152
    float* tt      = p + 2097152;              // 2097152
    float* W5T     = p;                        // reuse (dead after layer 4)
    float* partial = tt;                       // reuse

    dim3 blk(256);

    // ---- layer 1: C=3, O=64 ----
    sq_kernel<3><<<32, blk, 0, stream>>>(x, sq);
    knn_kernel<3><<<BB * (NN / 4), blk, 0, stream>>>(x, sq, idx);
    pt_kernel<3, 16><<<BB * (64 / 16) * (NN / 256), blk, 0, stream>>>(x, W1, p, tt, 64);
    edge_kernel<<<BB * 64, blk, 0, stream>>>(p, tt, idx, g1, b1, x1, 64);

    // ---- layer 2: C=64, O=64 ----
    sq_kernel<64><<<32, blk, 0, stream>>>(x1, sq);
    knn_kernel<64><<<BB * (NN / 4), blk, 0, stream>>>(x1, sq, idx);
    pt_kernel<64, 16><<<BB * (64 / 16) * (NN / 256), blk, 0, stream>>>(x1, W2, p, tt, 64);
    edge_kernel<<<BB * 64, blk, 0, stream>>>(p, tt, idx, g2, b2, x2, 64);

    // ---- layer 3: C=64, O=128 ----
    sq_kernel<64><<<32, blk, 0, stream>>>(x2, sq);
    knn_kernel<64><<<BB * (NN / 4), blk, 0, stream>>>(x2, sq, idx);
    pt_kernel<64, 16><<<BB * (128 / 16) * (NN / 256), blk, 0, stream>>>(x2, W3, p, tt, 128);
    edge_kernel<<<BB * 128, blk, 0, stream>>>(p, tt, idx, g3, b3, x3, 128);

    // ---- layer 4: C=128, O=256 ----
    sq_kernel<128><<<32, blk, 0, stream>>>(x3, sq);
    knn_kernel<128><<<BB * (NN / 4), blk, 0, stream>>>(x3, sq, idx);
    pt_kernel<128, 16><<<BB * (256 / 16) * (NN / 256), blk, 0, stream>>>(x3, W4, p, tt, 256);
    edge_kernel<<<BB * 256, blk, 0, stream>>>(p, tt, idx, g4, b4, x4, 256);

    // ---- layer 5: C=256, O=1024, fused max over n ----
    transpose_kernel<<<dim3(8, 32), dim3(32, 8), 0, stream>>>(W5, W5T);
    final_kernel<<<BB * 16 * 32, blk, 0, stream>>>(x4, W5T, g5, b5, partial);
    reduce32_kernel<<<16, blk, 0, stream>>>(partial, (float*)d_out);
}

// Round 8
// 588.816 us; speedup vs baseline: 1.7894x; 1.0813x over previous
//
#include <hip/hip_runtime.h>
#include <math.h>

#define BB 4
#define NN 2048
#define KK 20
#define INFPK 0xFFFFFFFFFFFFFFFFull

static __device__ __forceinline__ float lrelu(float z) {
    return z >= 0.f ? z : 0.2f * z;
}

// 64-bit full-wave min via paired 32-bit DPP (row_shr 1,2,4,8 + row_bcast 15,31),
// broadcast via readlane 63. 32-bit version of this exact sequence validated on
// this HW in R7 (passed). OOB lanes keep old=0xFFFFFFFF = identity for min.
template<int CTRL>
static __device__ __forceinline__ unsigned long long dpp_min64_step(unsigned long long v) {
    unsigned lo = (unsigned)__builtin_amdgcn_update_dpp(
        (int)0xFFFFFFFFu, (int)(unsigned)v, CTRL, 0xF, 0xF, false);
    unsigned hi = (unsigned)__builtin_amdgcn_update_dpp(
        (int)0xFFFFFFFFu, (int)(unsigned)(v >> 32), CTRL, 0xF, 0xF, false);
    unsigned long long t = ((unsigned long long)hi << 32) | lo;
    return t < v ? t : v;
}
static __device__ __forceinline__ unsigned long long wave_min64_bcast(unsigned long long v) {
    v = dpp_min64_step<0x111>(v);
    v = dpp_min64_step<0x112>(v);
    v = dpp_min64_step<0x114>(v);
    v = dpp_min64_step<0x118>(v);
    v = dpp_min64_step<0x142>(v);
    v = dpp_min64_step<0x143>(v);
    unsigned lo = (unsigned)__builtin_amdgcn_readlane((int)(unsigned)v, 63);
    unsigned hi = (unsigned)__builtin_amdgcn_readlane((int)(unsigned)(v >> 32), 63);
    return ((unsigned long long)hi << 32) | lo;
}

// ---------------- sq: per-point squared norm ----------------
template<int C>
__global__ __launch_bounds__(256) void sq_kernel(const float* __restrict__ x,
                                                 float* __restrict__ sq) {
    int i = blockIdx.x * 256 + threadIdx.x;
    if (i >= BB * NN) return;
    int b = i / NN, n = i - b * NN;
    const float* xb = x + (size_t)b * C * NN + n;
    float s = 0.f;
    #pragma unroll
    for (int c = 0; c < C; ++c) {
        float v = xb[(size_t)c * NN];
        s = fmaf(v, v, s);
    }
    sq[i] = s;
}

// ---------------- knn: top-20 smallest distance indices ----------------
// Block = 256 threads (4 waves) = (b, 4 queries); wave owns ONE query.
// Distance phase: block-cooperative (unchanged from R7, bit-identical values),
// keys stored quad-XOR-swizzled in LDS (conflict-reduced b128 reads).
// Selection: per-lane sorted top-4 queue of packed u64 pk=(key<<12)|j held in
// 4 named u64 registers (static compare-swap insert — no arrays, no LDS
// re-scan per round). Per round: ONE u64 DPP-min chain over the 64 heads;
// winner pops (static shift). Rare refill (lane emptied but has candidates
// left, P~1e-3/query): re-read its 8 chunks filtered by pk > last-popped.
// u64 min on distinct pk == exact (d, j) lexicographic — matches lax.top_k.
template<int C>
__global__ __launch_bounds__(256, 4) void knn_kernel(const float* __restrict__ x,
                                                     const float* __restrict__ sq,
                                                     int* __restrict__ idx) {
    const int QT = 4;
    __shared__ unsigned dl[QT][NN];   // 32 KB swizzled keys
    __shared__ float xq[QT][C];
    __shared__ float sqq[QT];
    int blk = blockIdx.x;
    int b = blk / (NN / QT);
    int q0 = (blk - b * (NN / QT)) * QT;
    int t = threadIdx.x;
    int lane = t & 63, wid = t >> 6;

    const float* xb = x + (size_t)b * C * NN;
    for (int e = t; e < QT * C; e += 256) {
        int q = e / C, c = e - q * C;
        xq[q][c] = xb[(size_t)c * NN + q0 + q];
    }
    if (t < QT) sqq[t] = sq[b * NN + q0 + t];
    __syncthreads();

    float acc[QT][8];
    #pragma unroll
    for (int q = 0; q < QT; ++q)
        #pragma unroll
        for (int s = 0; s < 8; ++s) acc[q][s] = 0.f;

    for (int c = 0; c < C; ++c) {
        float xj[8];
        #pragma unroll
        for (int s = 0; s < 8; ++s) xj[s] = xb[(size_t)c * NN + t + s * 256];
        #pragma unroll
        for (int q = 0; q < QT; ++q) {
            float xqc = xq[q][c];
            #pragma unroll
            for (int s = 0; s < 8; ++s) acc[q][s] = fmaf(xqc, xj[s], acc[q][s]);
        }
    }
    float sqj[8];
    #pragma unroll
    for (int s = 0; s < 8; ++s) sqj[s] = sq[b * NN + t + s * 256];

    // d = sq_i + sq_j - 2*inner (bit-identical expression to R2..R7), monotone
    // u32 key, stored at swizzled word W(j) = (j&~31)|((((j>>2)^(j>>5))&7)<<2)|(j&3).
    #pragma unroll
    for (int q = 0; q < QT; ++q) {
        float sqi = sqq[q];
        #pragma unroll
        for (int s = 0; s < 8; ++s) {
            float d = sqi + sqj[s] - 2.f * acc[q][s];
            unsigned u = __float_as_uint(d);
            unsigned key = u ^ ((unsigned)((int)u >> 31) | 0x80000000u);
            int j = s * 256 + t;
            int w = (j & ~31) | ((((j >> 2) ^ (j >> 5)) & 7) << 2) | (j & 3);
            dl[q][w] = key;
        }
    }
    __syncthreads();

    unsigned* dq = &dl[wid][0];
    int r7 = lane & 7;
    int lanebase = lane << 5;

    unsigned long long h0 = INFPK, h1 = INFPK, h2 = INFPK, h3 = INFPK;

    // sorted-4 insert: new list = 4 smallest of {h0..h3, v}, order preserved.
#define PK_INS(KEY, LO) {                                                     \
        unsigned long long v =                                                \
            ((unsigned long long)(KEY) << 12) | (unsigned)(lanebase + (LO));  \
        if (v < h3) {                                                         \
            unsigned long long nh3 = h2 > v ? h2 : v;                         \
            unsigned long long t2  = h2 < v ? h2 : v;                         \
            unsigned long long nh2 = h1 > t2 ? h1 : t2;                       \
            unsigned long long t1  = h1 < v ? h1 : v;                         \
            unsigned long long nh1 = h0 > t1 ? h0 : t1;                       \
            unsigned long long nh0 = h0 < v ? h0 : v;                         \
            h0 = nh0; h1 = nh1; h2 = nh2; h3 = nh3;                           \
        } }
#define PK_INS_THR(KEY, LO) {                                                 \
        unsigned long long v =                                                \
            ((unsigned long long)(KEY) << 12) | (unsigned)(lanebase + (LO));  \
        if (v > thr && v < h3) {                                              \
            unsigned long long nh3 = h2 > v ? h2 : v;                         \
            unsigned long long t2  = h2 < v ? h2 : v;                         \
            unsigned long long nh2 = h1 > t2 ? h1 : t2;                       \
            unsigned long long t1  = h1 < v ? h1 : v;                         \
            unsigned long long nh1 = h0 > t1 ? h0 : t1;                       \
            unsigned long long nh0 = h0 < v ? h0 : v;                         \
            h0 = nh0; h1 = nh1; h2 = nh2; h3 = nh3;                           \
        } }
#define CHUNK_RD(c) uint4 V##c = *(const uint4*)(dq + lanebase + (((c) ^ r7) << 2));
#define CHUNK_INS(c)     { PK_INS(V##c.x, 4*(c)+0) PK_INS(V##c.y, 4*(c)+1)        \
                           PK_INS(V##c.z, 4*(c)+2) PK_INS(V##c.w, 4*(c)+3) }
#define CHUNK_INS_THR(c) { PK_INS_THR(V##c.x, 4*(c)+0) PK_INS_THR(V##c.y, 4*(c)+1) \
                           PK_INS_THR(V##c.z, 4*(c)+2) PK_INS_THR(V##c.w, 4*(c)+3) }

    {   // build: one pass over the lane's 32 candidates
        CHUNK_RD(0) CHUNK_RD(1) CHUNK_RD(2) CHUNK_RD(3)
        CHUNK_RD(4) CHUNK_RD(5) CHUNK_RD(6) CHUNK_RD(7)
        CHUNK_INS(0) CHUNK_INS(1) CHUNK_INS(2) CHUNK_INS(3)
        CHUNK_INS(4) CHUNK_INS(5) CHUNK_INS(6) CHUNK_INS(7)
    }

    int* orow = idx + (size_t)(b * NN + q0 + wid) * KK;
    unsigned long long thr = 0;
    int popped = 0;
    #pragma unroll 1
    for (int rr = 0; rr < KK; ++rr) {
        unsigned long long g = wave_min64_bcast(h0);
        if (lane == 0) orow[rr] = (int)(g & 0xFFFu);
        if (h0 == g) {
            thr = g;
            ++popped;
            h0 = h1; h1 = h2; h2 = h3; h3 = INFPK;
            if (h0 == INFPK && popped < 32) {   // rare refill
                CHUNK_RD(0) CHUNK_RD(1) CHUNK_RD(2) CHUNK_RD(3)
                CHUNK_RD(4) CHUNK_RD(5) CHUNK_RD(6) CHUNK_RD(7)
                CHUNK_INS_THR(0) CHUNK_INS_THR(1) CHUNK_INS_THR(2) CHUNK_INS_THR(3)
                CHUNK_INS_THR(4) CHUNK_INS_THR(5) CHUNK_INS_THR(6) CHUNK_INS_THR(7)
            }
        }
    }
#undef PK_INS
#undef PK_INS_THR
#undef CHUNK_RD
#undef CHUNK_INS
#undef CHUNK_INS_THR
}

// ---------------- p/t: p = Wn·x, t = (Wc-Wn)·x ----------------
template<int C, int OT>
__global__ __launch_bounds__(256) void pt_kernel(const float* __restrict__ x,
                                                 const float* __restrict__ W,
                                                 float* __restrict__ p,
                                                 float* __restrict__ tt,
                                                 int O) {
    const int NB = NN / 256;
    int blk = blockIdx.x;
    int nb = blk % NB;
    int rest = blk / NB;
    int nob = O / OT;
    int ob = rest % nob;
    int b = rest / nob;
    int t = threadIdx.x;
    int n = nb * 256 + t;
    __shared__ float wn[OT][C], wd[OT][C];
    for (int e = t; e < OT * C; e += 256) {
        int o = e / C, c = e - o * C;
        float a = W[(size_t)(ob * OT + o) * (2 * C) + c];
        float b2 = W[(size_t)(ob * OT + o) * (2 * C) + C + c];
        wn[o][c] = a;
        wd[o][c] = b2 - a;
    }
    __syncthreads();
    float ap[OT], at[OT];
    #pragma unroll
    for (int o = 0; o < OT; ++o) { ap[o] = 0.f; at[o] = 0.f; }
    const float* xb = x + (size_t)b * C * NN + n;
    for (int c = 0; c < C; ++c) {
        float xv = xb[(size_t)c * NN];
        #pragma unroll
        for (int o = 0; o < OT; ++o) {
            ap[o] = fmaf(wn[o][c], xv, ap[o]);
            at[o] = fmaf(wd[o][c], xv, at[o]);
        }
    }
    size_t base = ((size_t)b * O + ob * OT) * NN + n;
    #pragma unroll
    for (int o = 0; o < OT; ++o) {
        p[base + (size_t)o * NN] = ap[o];
        tt[base + (size_t)o * NN] = at[o];
    }
}

// ---------------- edge max: out[b,o,i] = max_k lrelu(scale*(p[j]+t_i)+beta) ----------------
__global__ __launch_bounds__(256) void edge_kernel(const float* __restrict__ p,
                                                   const float* __restrict__ tt,
                                                   const int* __restrict__ idx,
                                                   const float* __restrict__ g,
                                                   const float* __restrict__ be,
                                                   float* __restrict__ out, int O) {
    int b = blockIdx.x / O, o = blockIdx.x - b * O;
    __shared__ float pl[NN];
    const float* pr = p + ((size_t)b * O + o) * NN;
    for (int e = threadIdx.x * 4; e < NN; e += 1024)
        *(float4*)&pl[e] = *(const float4*)&pr[e];
    __syncthreads();
    float scale = g[o] / sqrtf(1.f + 1e-5f);
    float beta = be[o];
    const float* tr = tt + ((size_t)b * O + o) * NN;
    float* orow = out + ((size_t)b * O + o) * NN;
    for (int i = threadIdx.x; i < NN; i += 256) {
        float ti = tr[i];
        const int4* ir4 = (const int4*)(idx + (size_t)(b * NN + i) * KK);
        int4 w0 = ir4[0], w1 = ir4[1], w2 = ir4[2], w3 = ir4[3], w4 = ir4[4];
        float m = -__builtin_inff();
        int js[20] = {w0.x, w0.y, w0.z, w0.w, w1.x, w1.y, w1.z, w1.w,
                      w2.x, w2.y, w2.z, w2.w, w3.x, w3.y, w3.z, w3.w,
                      w4.x, w4.y, w4.z, w4.w};
        #pragma unroll
        for (int k = 0; k < KK; ++k) {
            float y = pl[js[k]] + ti;
            m = fmaxf(m, lrelu(fmaf(scale, y, beta)));
        }
        orow[i] = m;
    }
}

// ---------------- transpose W5 [1024][256] -> W5T [256][1024] ----------------
__global__ __launch_bounds__(256) void transpose_kernel(const float* __restrict__ W,
                                                        float* __restrict__ WT) {
    __shared__ float tile[32][33];
    int c0 = blockIdx.x * 32, o0 = blockIdx.y * 32;
    int tx = threadIdx.x, ty = threadIdx.y;   // 32 x 8
    #pragma unroll
    for (int i = 0; i < 32; i += 8)
        tile[ty + i][tx] = W[(size_t)(o0 + ty + i) * 256 + c0 + tx];
    __syncthreads();
    #pragma unroll
    for (int i = 0; i < 32; i += 8)
        WT[(size_t)(c0 + ty + i) * 1024 + o0 + tx] = tile[tx][ty + i];
}

// ---------------- final: register-tiled GEMM + fused lrelu + max over n ----------------
__global__ __launch_bounds__(256) void final_kernel(const float* __restrict__ x4,
                                                    const float* __restrict__ W5T,
                                                    const float* __restrict__ g,
                                                    const float* __restrict__ be,
                                                    float* __restrict__ partial) {
    const int CC = 256;
    __shared__ float xs[64][64];
    __shared__ float ws[64][64];
    int blk = blockIdx.x;
    int nb = blk & 31;
    int ob = (blk >> 5) & 15;
    int b  = blk >> 9;
    int t = threadIdx.x;
    int tn = t & 15, to = t >> 4;

    float acc[4][4];
    #pragma unroll
    for (int i = 0; i < 4; ++i)
        #pragma unroll
        for (int j = 0; j < 4; ++j) acc[i][j] = 0.f;

    for (int c0 = 0; c0 < CC; c0 += 64) {
        __syncthreads();
        #pragma unroll
        for (int e = t * 4; e < 64 * 64; e += 1024) {
            int c = e >> 6, n = e & 63;
            *(float4*)&xs[c][n] =
                *(const float4*)&x4[((size_t)b * CC + c0 + c) * NN + nb * 64 + n];
        }
        #pragma unroll
        for (int e = t * 4; e < 64 * 64; e += 1024) {
            int c = e >> 6, o = e & 63;
            *(float4*)&ws[c][o] =
                *(const float4*)&W5T[(size_t)(c0 + c) * 1024 + ob * 64 + o];
        }
        __syncthreads();
        for (int c = 0; c < 64; ++c) {
            float4 xv = *(float4*)&xs[c][tn * 4];
            float4 wv = *(float4*)&ws[c][to * 4];
            acc[0][0] = fmaf(wv.x, xv.x, acc[0][0]);
            acc[0][1] = fmaf(wv.x, xv.y, acc[0][1]);
            acc[0][2] = fmaf(wv.x, xv.z, acc[0][2]);
            acc[0][3] = fmaf(wv.x, xv.w, acc[0][3]);
            acc[1][0] = fmaf(wv.y, xv.x, acc[1][0]);
            acc[1][1] = fmaf(wv.y, xv.y, acc[1][1]);
            acc[1][2] = fmaf(wv.y, xv.z, acc[1][2]);
            acc[1][3] = fmaf(wv.y, xv.w, acc[1][3]);
            acc[2][0] = fmaf(wv.z, xv.x, acc[2][0]);
            acc[2][1] = fmaf(wv.z, xv.y, acc[2][1]);
            acc[2][2] = fmaf(wv.z, xv.z, acc[2][2]);
            acc[2][3] = fmaf(wv.z, xv.w, acc[2][3]);
            acc[3][0] = fmaf(wv.w, xv.x, acc[3][0]);
            acc[3][1] = fmaf(wv.w, xv.y, acc[3][1]);
            acc[3][2] = fmaf(wv.w, xv.z, acc[3][2]);
            acc[3][3] = fmaf(wv.w, xv.w, acc[3][3]);
        }
    }

    float rs = 1.f / sqrtf(1.f + 1e-5f);
    #pragma unroll
    for (int i = 0; i < 4; ++i) {
        int o = ob * 64 + to * 4 + i;
        float scale = g[o] * rs, beta = be[o];
        float m = -__builtin_inff();
        #pragma unroll
        for (int j = 0; j < 4; ++j)
            m = fmaxf(m, lrelu(fmaf(scale, acc[i][j], beta)));
        #pragma unroll
        for (int off = 8; off >= 1; off >>= 1)
            m = fmaxf(m, __shfl_xor(m, off));
        if (tn == 0)
            partial[(size_t)(nb * BB + b) * 1024 + o] = m;
    }
}

__global__ __launch_bounds__(256) void reduce32_kernel(const float* __restrict__ partial,
                                                       float* __restrict__ out) {
    int i = blockIdx.x * 256 + threadIdx.x;
    if (i >= BB * 1024) return;
    int b = i >> 10, o = i & 1023;
    float m = -__builtin_inff();
    #pragma unroll
    for (int nb = 0; nb < 32; ++nb)
        m = fmaxf(m, partial[(size_t)(nb * BB + b) * 1024 + o]);
    out[i] = m;
}

extern "C" void kernel_launch(void* const* d_in, const int* in_sizes, int n_in,
                              void* d_out, int out_size, void* d_ws, size_t ws_size,
                              hipStream_t stream) {
    const float* x  = (const float*)d_in[0];
    const float* W1 = (const float*)d_in[1];
    const float* g1 = (const float*)d_in[2];
    const float* b1 = (const float*)d_in[3];
    const float* W2 = (const float*)d_in[4];
    const float* g2 = (const float*)d_in[5];
    const float* b2 = (const float*)d_in[6];
    const float* W3 = (const float*)d_in[7];
    const float* g3 = (const float*)d_in[8];
    const float* b3 = (const float*)d_in[9];
    const float* W4 = (const float*)d_in[10];
    const float* g4 = (const float*)d_in[11];
    const float* b4 = (const float*)d_in[12];
    const float* W5 = (const float*)d_in[13];
    const float* g5 = (const float*)d_in[14];
    const float* b5 = (const float*)d_in[15];

    float* ws = (float*)d_ws;
    float* sq      = ws;                       // 8192
    int*   idx     = (int*)(ws + 8192);        // 163840 ints
    float* x1      = ws + 8192 + 163840;       // 524288
    float* x2      = x1 + 524288;              // 524288
    float* x3      = x2 + 524288;              // 1048576
    float* x4      = x3 + 1048576;             // 2097152
    float* p       = x4 + 2097152;             // 2097152
    float* tt      = p + 2097152;              // 2097152
    float* W5T     = p;                        // reuse (dead after layer 4)
    float* partial = tt;                       // reuse

    dim3 blk(256);

    // ---- layer 1: C=3, O=64 ----
    sq_kernel<3><<<32, blk, 0, stream>>>(x, sq);
    knn_kernel<3><<<BB * (NN / 4), blk, 0, stream>>>(x, sq, idx);
    pt_kernel<3, 16><<<BB * (64 / 16) * (NN / 256), blk, 0, stream>>>(x, W1, p, tt, 64);
    edge_kernel<<<BB * 64, blk, 0, stream>>>(p, tt, idx, g1, b1, x1, 64);

    // ---- layer 2: C=64, O=64 ----
    sq_kernel<64><<<32, blk, 0, stream>>>(x1, sq);
    knn_kernel<64><<<BB * (NN / 4), blk, 0, stream>>>(x1, sq, idx);
    pt_kernel<64, 16><<<BB * (64 / 16) * (NN / 256), blk, 0, stream>>>(x1, W2, p, tt, 64);
    edge_kernel<<<BB * 64, blk, 0, stream>>>(p, tt, idx, g2, b2, x2, 64);

    // ---- layer 3: C=64, O=128 ----
    sq_kernel<64><<<32, blk, 0, stream>>>(x2, sq);
    knn_kernel<64><<<BB * (NN / 4), blk, 0, stream>>>(x2, sq, idx);
    pt_kernel<64, 16><<<BB * (128 / 16) * (NN / 256), blk, 0, stream>>>(x2, W3, p, tt, 128);
    edge_kernel<<<BB * 128, blk, 0, stream>>>(p, tt, idx, g3, b3, x3, 128);

    // ---- layer 4: C=128, O=256 ----
    sq_kernel<128><<<32, blk, 0, stream>>>(x3, sq);
    knn_kernel<128><<<BB * (NN / 4), blk, 0, stream>>>(x3, sq, idx);
    pt_kernel<128, 16><<<BB * (256 / 16) * (NN / 256), blk, 0, stream>>>(x3, W4, p, tt, 256);
    edge_kernel<<<BB * 256, blk, 0, stream>>>(p, tt, idx, g4, b4, x4, 256);

    // ---- layer 5: C=256, O=1024, fused max over n ----
    transpose_kernel<<<dim3(8, 32), dim3(32, 8), 0, stream>>>(W5, W5T);
    final_kernel<<<BB * 16 * 32, blk, 0, stream>>>(x4, W5T, g5, b5, partial);
    reduce32_kernel<<<16, blk, 0, stream>>>(partial, (float*)d_out);
}

// Round 9
// 562.107 us; speedup vs baseline: 1.8744x; 1.0475x over previous
//
#include <hip/hip_runtime.h>
#include <math.h>

#define BB 4
#define NN 2048
#define KK 20
#define INFPK 0xFFFFFFFFFFFFFFFFull

static __device__ __forceinline__ float lrelu(float z) {
    return z >= 0.f ? z : 0.2f * z;
}

// 64-bit full-wave min via paired 32-bit DPP (row_shr 1,2,4,8 + row_bcast 15,31),
// broadcast via readlane 63. Validated on this HW in R7/R8 (passed).
template<int CTRL>
static __device__ __forceinline__ unsigned long long dpp_min64_step(unsigned long long v) {
    unsigned lo = (unsigned)__builtin_amdgcn_update_dpp(
        (int)0xFFFFFFFFu, (int)(unsigned)v, CTRL, 0xF, 0xF, false);
    unsigned hi = (unsigned)__builtin_amdgcn_update_dpp(
        (int)0xFFFFFFFFu, (int)(unsigned)(v >> 32), CTRL, 0xF, 0xF, false);
    unsigned long long t = ((unsigned long long)hi << 32) | lo;
    return t < v ? t : v;
}
static __device__ __forceinline__ unsigned long long wave_min64_bcast(unsigned long long v) {
    v = dpp_min64_step<0x111>(v);
    v = dpp_min64_step<0x112>(v);
    v = dpp_min64_step<0x114>(v);
    v = dpp_min64_step<0x118>(v);
    v = dpp_min64_step<0x142>(v);
    v = dpp_min64_step<0x143>(v);
    unsigned lo = (unsigned)__builtin_amdgcn_readlane((int)(unsigned)v, 63);
    unsigned hi = (unsigned)__builtin_amdgcn_readlane((int)(unsigned)(v >> 32), 63);
    return ((unsigned long long)hi << 32) | lo;
}

// ---------------- sq: per-point squared norm ----------------
template<int C>
__global__ __launch_bounds__(256) void sq_kernel(const float* __restrict__ x,
                                                 float* __restrict__ sq) {
    int i = blockIdx.x * 256 + threadIdx.x;
    if (i >= BB * NN) return;
    int b = i / NN, n = i - b * NN;
    const float* xb = x + (size_t)b * C * NN + n;
    float s = 0.f;
    #pragma unroll
    for (int c = 0; c < C; ++c) {
        float v = xb[(size_t)c * NN];
        s = fmaf(v, v, s);
    }
    sq[i] = s;
}

// ---------------- knn: top-20 smallest distance indices ----------------
// Block = 512 threads (8 waves) = (b, 8 queries); wave owns ONE query.
// Distance phase: thread t owns j in {4t..4t+3} -> ONE float4 load per channel
// (was 8 scalar loads + 8 addr calcs in R8 — load/addr issue dominated), and
// QT=8 halves the per-batch redundant x row-reads (L2 traffic halved).
// FMA chain per (q,j) is ascending-c — distances bit-identical to R2..R8.
// Selection (validated R8): per-lane sorted top-4 queue of pk=(key<<12)|j in 4
// named u64 regs; per round ONE u64 DPP-min chain; rare threshold refill.
// u64 min on distinct pk == exact (d, j) lexicographic — matches lax.top_k.
template<int C>
__global__ __launch_bounds__(512) void knn_kernel(const float* __restrict__ x,
                                                  const float* __restrict__ sq,
                                                  int* __restrict__ idx) {
    const int QT = 8;
    __shared__ unsigned dl[QT][NN];   // 64 KB swizzled keys
    __shared__ float xq[QT][C];
    __shared__ float sqq[QT];
    int blk = blockIdx.x;
    int b = blk / (NN / QT);
    int q0 = (blk - b * (NN / QT)) * QT;
    int t = threadIdx.x;
    int lane = t & 63, wid = t >> 6;

    const float* xb = x + (size_t)b * C * NN;
    for (int e = t; e < QT * C; e += 512) {
        int q = e / C, c = e - q * C;
        xq[q][c] = xb[(size_t)c * NN + q0 + q];
    }
    if (t < QT) sqq[t] = sq[b * NN + q0 + t];
    __syncthreads();

    float acc[QT][4];
    #pragma unroll
    for (int q = 0; q < QT; ++q)
        #pragma unroll
        for (int u = 0; u < 4; ++u) acc[q][u] = 0.f;

    for (int c = 0; c < C; ++c) {
        float4 xj = *(const float4*)&xb[(size_t)c * NN + 4 * t];
        #pragma unroll
        for (int q = 0; q < QT; ++q) {
            float xqc = xq[q][c];
            acc[q][0] = fmaf(xqc, xj.x, acc[q][0]);
            acc[q][1] = fmaf(xqc, xj.y, acc[q][1]);
            acc[q][2] = fmaf(xqc, xj.z, acc[q][2]);
            acc[q][3] = fmaf(xqc, xj.w, acc[q][3]);
        }
    }
    float4 sqj = *(const float4*)&sq[b * NN + 4 * t];
    float sqju[4] = {sqj.x, sqj.y, sqj.z, sqj.w};

    // d = sq_i + sq_j - 2*inner (bit-identical expression), monotone u32 key,
    // stored swizzled: j=4t+u -> word ((t>>3)<<5) | (((t^(t>>3))&7)<<2) | u
    // (contiguous quad per (thread, q) -> single uint4 store).
    int wbase = ((t >> 3) << 5) | (((t ^ (t >> 3)) & 7) << 2);
    #pragma unroll
    for (int q = 0; q < QT; ++q) {
        float sqi = sqq[q];
        uint4 kv;
        unsigned ks[4];
        #pragma unroll
        for (int u = 0; u < 4; ++u) {
            float d = sqi + sqju[u] - 2.f * acc[q][u];
            unsigned v = __float_as_uint(d);
            ks[u] = v ^ ((unsigned)((int)v >> 31) | 0x80000000u);
        }
        kv.x = ks[0]; kv.y = ks[1]; kv.z = ks[2]; kv.w = ks[3];
        *(uint4*)&dl[q][wbase] = kv;
    }
    __syncthreads();

    unsigned* dq = &dl[wid][0];
    int r7 = lane & 7;
    int lanebase = lane << 5;

    unsigned long long h0 = INFPK, h1 = INFPK, h2 = INFPK, h3 = INFPK;

#define PK_INS(KEY, LO) {                                                     \
        unsigned long long v =                                                \
            ((unsigned long long)(KEY) << 12) | (unsigned)(lanebase + (LO));  \
        if (v < h3) {                                                         \
            unsigned long long nh3 = h2 > v ? h2 : v;                         \
            unsigned long long t2  = h2 < v ? h2 : v;                         \
            unsigned long long nh2 = h1 > t2 ? h1 : t2;                       \
            unsigned long long t1  = h1 < v ? h1 : v;                         \
            unsigned long long nh1 = h0 > t1 ? h0 : t1;                       \
            unsigned long long nh0 = h0 < v ? h0 : v;                         \
            h0 = nh0; h1 = nh1; h2 = nh2; h3 = nh3;                           \
        } }
#define PK_INS_THR(KEY, LO) {                                                 \
        unsigned long long v =                                                \
            ((unsigned long long)(KEY) << 12) | (unsigned)(lanebase + (LO));  \
        if (v > thr && v < h3) {                                              \
            unsigned long long nh3 = h2 > v ? h2 : v;                         \
            unsigned long long t2  = h2 < v ? h2 : v;                         \
            unsigned long long nh2 = h1 > t2 ? h1 : t2;                       \
            unsigned long long t1  = h1 < v ? h1 : v;                         \
            unsigned long long nh1 = h0 > t1 ? h0 : t1;                       \
            unsigned long long nh0 = h0 < v ? h0 : v;                         \
            h0 = nh0; h1 = nh1; h2 = nh2; h3 = nh3;                           \
        } }
#define CHUNK_RD(c) uint4 V##c = *(const uint4*)(dq + lanebase + (((c) ^ r7) << 2));
#define CHUNK_INS(c)     { PK_INS(V##c.x, 4*(c)+0) PK_INS(V##c.y, 4*(c)+1)        \
                           PK_INS(V##c.z, 4*(c)+2) PK_INS(V##c.w, 4*(c)+3) }
#define CHUNK_INS_THR(c) { PK_INS_THR(V##c.x, 4*(c)+0) PK_INS_THR(V##c.y, 4*(c)+1) \
                           PK_INS_THR(V##c.z, 4*(c)+2) PK_INS_THR(V##c.w, 4*(c)+3) }

    {   // build: one pass over the lane's 32 candidates
        CHUNK_RD(0) CHUNK_RD(1) CHUNK_RD(2) CHUNK_RD(3)
        CHUNK_RD(4) CHUNK_RD(5) CHUNK_RD(6) CHUNK_RD(7)
        CHUNK_INS(0) CHUNK_INS(1) CHUNK_INS(2) CHUNK_INS(3)
        CHUNK_INS(4) CHUNK_INS(5) CHUNK_INS(6) CHUNK_INS(7)
    }

    int* orow = idx + (size_t)(b * NN + q0 + wid) * KK;
    unsigned long long thr = 0;
    int popped = 0;
    #pragma unroll 1
    for (int rr = 0; rr < KK; ++rr) {
        unsigned long long g = wave_min64_bcast(h0);
        if (lane == 0) orow[rr] = (int)(g & 0xFFFu);
        if (h0 == g) {
            thr = g;
            ++popped;
            h0 = h1; h1 = h2; h2 = h3; h3 = INFPK;
            if (h0 == INFPK && popped < 32) {   // rare refill
                CHUNK_RD(0) CHUNK_RD(1) CHUNK_RD(2) CHUNK_RD(3)
                CHUNK_RD(4) CHUNK_RD(5) CHUNK_RD(6) CHUNK_RD(7)
                CHUNK_INS_THR(0) CHUNK_INS_THR(1) CHUNK_INS_THR(2) CHUNK_INS_THR(3)
                CHUNK_INS_THR(4) CHUNK_INS_THR(5) CHUNK_INS_THR(6) CHUNK_INS_THR(7)
            }
        }
    }
#undef PK_INS
#undef PK_INS_THR
#undef CHUNK_RD
#undef CHUNK_INS
#undef CHUNK_INS_THR
}

// ---------------- p/t: p = Wn·x, t = (Wc-Wn)·x ----------------
template<int C, int OT>
__global__ __launch_bounds__(256) void pt_kernel(const float* __restrict__ x,
                                                 const float* __restrict__ W,
                                                 float* __restrict__ p,
                                                 float* __restrict__ tt,
                                                 int O) {
    const int NB = NN / 256;
    int blk = blockIdx.x;
    int nb = blk % NB;
    int rest = blk / NB;
    int nob = O / OT;
    int ob = rest % nob;
    int b = rest / nob;
    int t = threadIdx.x;
    int n = nb * 256 + t;
    __shared__ float wn[OT][C], wd[OT][C];
    for (int e = t; e < OT * C; e += 256) {
        int o = e / C, c = e - o * C;
        float a = W[(size_t)(ob * OT + o) * (2 * C) + c];
        float b2 = W[(size_t)(ob * OT + o) * (2 * C) + C + c];
        wn[o][c] = a;
        wd[o][c] = b2 - a;
    }
    __syncthreads();
    float ap[OT], at[OT];
    #pragma unroll
    for (int o = 0; o < OT; ++o) { ap[o] = 0.f; at[o] = 0.f; }
    const float* xb = x + (size_t)b * C * NN + n;
    for (int c = 0; c < C; ++c) {
        float xv = xb[(size_t)c * NN];
        #pragma unroll
        for (int o = 0; o < OT; ++o) {
            ap[o] = fmaf(wn[o][c], xv, ap[o]);
            at[o] = fmaf(wd[o][c], xv, at[o]);
        }
    }
    size_t base = ((size_t)b * O + ob * OT) * NN + n;
    #pragma unroll
    for (int o = 0; o < OT; ++o) {
        p[base + (size_t)o * NN] = ap[o];
        tt[base + (size_t)o * NN] = at[o];
    }
}

// ---------------- edge max: out[b,o,i] = max_k lrelu(scale*(p[j]+t_i)+beta) ----------------
__global__ __launch_bounds__(256) void edge_kernel(const float* __restrict__ p,
                                                   const float* __restrict__ tt,
                                                   const int* __restrict__ idx,
                                                   const float* __restrict__ g,
                                                   const float* __restrict__ be,
                                                   float* __restrict__ out, int O) {
    int b = blockIdx.x / O, o = blockIdx.x - b * O;
    __shared__ float pl[NN];
    const float* pr = p + ((size_t)b * O + o) * NN;
    for (int e = threadIdx.x * 4; e < NN; e += 1024)
        *(float4*)&pl[e] = *(const float4*)&pr[e];
    __syncthreads();
    float scale = g[o] / sqrtf(1.f + 1e-5f);
    float beta = be[o];
    const float* tr = tt + ((size_t)b * O + o) * NN;
    float* orow = out + ((size_t)b * O + o) * NN;
    for (int i = threadIdx.x; i < NN; i += 256) {
        float ti = tr[i];
        const int4* ir4 = (const int4*)(idx + (size_t)(b * NN + i) * KK);
        int4 w0 = ir4[0], w1 = ir4[1], w2 = ir4[2], w3 = ir4[3], w4 = ir4[4];
        float m = -__builtin_inff();
        int js[20] = {w0.x, w0.y, w0.z, w0.w, w1.x, w1.y, w1.z, w1.w,
                      w2.x, w2.y, w2.z, w2.w, w3.x, w3.y, w3.z, w3.w,
                      w4.x, w4.y, w4.z, w4.w};
        #pragma unroll
        for (int k = 0; k < KK; ++k) {
            float y = pl[js[k]] + ti;
            m = fmaxf(m, lrelu(fmaf(scale, y, beta)));
        }
        orow[i] = m;
    }
}

// ---------------- transpose W5 [1024][256] -> W5T [256][1024] ----------------
__global__ __launch_bounds__(256) void transpose_kernel(const float* __restrict__ W,
                                                        float* __restrict__ WT) {
    __shared__ float tile[32][33];
    int c0 = blockIdx.x * 32, o0 = blockIdx.y * 32;
    int tx = threadIdx.x, ty = threadIdx.y;   // 32 x 8
    #pragma unroll
    for (int i = 0; i < 32; i += 8)
        tile[ty + i][tx] = W[(size_t)(o0 + ty + i) * 256 + c0 + tx];
    __syncthreads();
    #pragma unroll
    for (int i = 0; i < 32; i += 8)
        WT[(size_t)(c0 + ty + i) * 1024 + o0 + tx] = tile[tx][ty + i];
}

// ---------------- final: register-tiled GEMM + fused lrelu + max over n ----------------
__global__ __launch_bounds__(256) void final_kernel(const float* __restrict__ x4,
                                                    const float* __restrict__ W5T,
                                                    const float* __restrict__ g,
                                                    const float* __restrict__ be,
                                                    float* __restrict__ partial) {
    const int CC = 256;
    __shared__ float xs[64][64];
    __shared__ float ws[64][64];
    int blk = blockIdx.x;
    int nb = blk & 31;
    int ob = (blk >> 5) & 15;
    int b  = blk >> 9;
    int t = threadIdx.x;
    int tn = t & 15, to = t >> 4;

    float acc[4][4];
    #pragma unroll
    for (int i = 0; i < 4; ++i)
        #pragma unroll
        for (int j = 0; j < 4; ++j) acc[i][j] = 0.f;

    for (int c0 = 0; c0 < CC; c0 += 64) {
        __syncthreads();
        #pragma unroll
        for (int e = t * 4; e < 64 * 64; e += 1024) {
            int c = e >> 6, n = e & 63;
            *(float4*)&xs[c][n] =
                *(const float4*)&x4[((size_t)b * CC + c0 + c) * NN + nb * 64 + n];
        }
        #pragma unroll
        for (int e = t * 4; e < 64 * 64; e += 1024) {
            int c = e >> 6, o = e & 63;
            *(float4*)&ws[c][o] =
                *(const float4*)&W5T[(size_t)(c0 + c) * 1024 + ob * 64 + o];
        }
        __syncthreads();
        for (int c = 0; c < 64; ++c) {
            float4 xv = *(float4*)&xs[c][tn * 4];
            float4 wv = *(float4*)&ws[c][to * 4];
            acc[0][0] = fmaf(wv.x, xv.x, acc[0][0]);
            acc[0][1] = fmaf(wv.x, xv.y, acc[0][1]);
            acc[0][2] = fmaf(wv.x, xv.z, acc[0][2]);
            acc[0][3] = fmaf(wv.x, xv.w, acc[0][3]);
            acc[1][0] = fmaf(wv.y, xv.x, acc[1][0]);
            acc[1][1] = fmaf(wv.y, xv.y, acc[1][1]);
            acc[1][2] = fmaf(wv.y, xv.z, acc[1][2]);
            acc[1][3] = fmaf(wv.y, xv.w, acc[1][3]);
            acc[2][0] = fmaf(wv.z, xv.x, acc[2][0]);
            acc[2][1] = fmaf(wv.z, xv.y, acc[2][1]);
            acc[2][2] = fmaf(wv.z, xv.z, acc[2][2]);
            acc[2][3] = fmaf(wv.z, xv.w, acc[2][3]);
            acc[3][0] = fmaf(wv.w, xv.x, acc[3][0]);
            acc[3][1] = fmaf(wv.w, xv.y, acc[3][1]);
            acc[3][2] = fmaf(wv.w, xv.z, acc[3][2]);
            acc[3][3] = fmaf(wv.w, xv.w, acc[3][3]);
        }
    }

    float rs = 1.f / sqrtf(1.f + 1e-5f);
    #pragma unroll
    for (int i = 0; i < 4; ++i) {
        int o = ob * 64 + to * 4 + i;
        float scale = g[o] * rs, beta = be[o];
        float m = -__builtin_inff();
        #pragma unroll
        for (int j = 0; j < 4; ++j)
            m = fmaxf(m, lrelu(fmaf(scale, acc[i][j], beta)));
        #pragma unroll
        for (int off = 8; off >= 1; off >>= 1)
            m = fmaxf(m, __shfl_xor(m, off));
        if (tn == 0)
            partial[(size_t)(nb * BB + b) * 1024 + o] = m;
    }
}

__global__ __launch_bounds__(256) void reduce32_kernel(const float* __restrict__ partial,
                                                       float* __restrict__ out) {
    int i = blockIdx.x * 256 + threadIdx.x;
    if (i >= BB * 1024) return;
    int b = i >> 10, o = i & 1023;
    float m = -__builtin_inff();
    #pragma unroll
    for (int nb = 0; nb < 32; ++nb)
        m = fmaxf(m, partial[(size_t)(nb * BB + b) * 1024 + o]);
    out[i] = m;
}

extern "C" void kernel_launch(void* const* d_in, const int* in_sizes, int n_in,
                              void* d_out, int out_size, void* d_ws, size_t ws_size,
                              hipStream_t stream) {
    const float* x  = (const float*)d_in[0];
    const float* W1 = (const float*)d_in[1];
    const float* g1 = (const float*)d_in[2];
    const float* b1 = (const float*)d_in[3];
    const float* W2 = (const float*)d_in[4];
    const float* g2 = (const float*)d_in[5];
    const float* b2 = (const float*)d_in[6];
    const float* W3 = (const float*)d_in[7];
    const float* g3 = (const float*)d_in[8];
    const float* b3 = (const float*)d_in[9];
    const float* W4 = (const float*)d_in[10];
    const float* g4 = (const float*)d_in[11];
    const float* b4 = (const float*)d_in[12];
    const float* W5 = (const float*)d_in[13];
    const float* g5 = (const float*)d_in[14];
    const float* b5 = (const float*)d_in[15];

    float* ws = (float*)d_ws;
    float* sq      = ws;                       // 8192
    int*   idx     = (int*)(ws + 8192);        // 163840 ints
    float* x1      = ws + 8192 + 163840;       // 524288
    float* x2      = x1 + 524288;              // 524288
    float* x3      = x2 + 524288;              // 1048576
    float* x4      = x3 + 1048576;             // 2097152
    float* p       = x4 + 2097152;             // 2097152
    float* tt      = p + 2097152;              // 2097152
    float* W5T     = p;                        // reuse (dead after layer 4)
    float* partial = tt;                       // reuse

    dim3 blk(256), kblk(512);

    // ---- layer 1: C=3, O=64 ----
    sq_kernel<3><<<32, blk, 0, stream>>>(x, sq);
    knn_kernel<3><<<BB * (NN / 8), kblk, 0, stream>>>(x, sq, idx);
    pt_kernel<3, 16><<<BB * (64 / 16) * (NN / 256), blk, 0, stream>>>(x, W1, p, tt, 64);
    edge_kernel<<<BB * 64, blk, 0, stream>>>(p, tt, idx, g1, b1, x1, 64);

    // ---- layer 2: C=64, O=64 ----
    sq_kernel<64><<<32, blk, 0, stream>>>(x1, sq);
    knn_kernel<64><<<BB * (NN / 8), kblk, 0, stream>>>(x1, sq, idx);
    pt_kernel<64, 16><<<BB * (64 / 16) * (NN / 256), blk, 0, stream>>>(x1, W2, p, tt, 64);
    edge_kernel<<<BB * 64, blk, 0, stream>>>(p, tt, idx, g2, b2, x2, 64);

    // ---- layer 3: C=64, O=128 ----
    sq_kernel<64><<<32, blk, 0, stream>>>(x2, sq);
    knn_kernel<64><<<BB * (NN / 8), kblk, 0, stream>>>(x2, sq, idx);
    pt_kernel<64, 16><<<BB * (128 / 16) * (NN / 256), blk, 0, stream>>>(x2, W3, p, tt, 128);
    edge_kernel<<<BB * 128, blk, 0, stream>>>(p, tt, idx, g3, b3, x3, 128);

    // ---- layer 4: C=128, O=256 ----
    sq_kernel<128><<<32, blk, 0, stream>>>(x3, sq);
    knn_kernel<128><<<BB * (NN / 8), kblk, 0, stream>>>(x3, sq, idx);
    pt_kernel<128, 16><<<BB * (256 / 16) * (NN / 256), blk, 0, stream>>>(x3, W4, p, tt, 256);
    edge_kernel<<<BB * 256, blk, 0, stream>>>(p, tt, idx, g4, b4, x4, 256);

    // ---- layer 5: C=256, O=1024, fused max over n ----
    transpose_kernel<<<dim3(8, 32), dim3(32, 8), 0, stream>>>(W5, W5T);
    final_kernel<<<BB * 16 * 32, blk, 0, stream>>>(x4, W5T, g5, b5, partial);
    reduce32_kernel<<<16, blk, 0, stream>>>(partial, (float*)d_out);
}

// Round 10
// 513.952 us; speedup vs baseline: 2.0501x; 1.0937x over previous
//
#include <hip/hip_runtime.h>
#include <math.h>

#define BB 4
#define NN 2048
#define KK 20
#define INFPK 0xFFFFFFFFFFFFFFFFull

static __device__ __forceinline__ float lrelu(float z) {
    return z >= 0.f ? z : 0.2f * z;
}

// 64-bit full-wave min via paired 32-bit DPP (row_shr 1,2,4,8 + row_bcast 15,31),
// broadcast via readlane 63. Validated on this HW in R7/R8/R9 (passed).
template<int CTRL>
static __device__ __forceinline__ unsigned long long dpp_min64_step(unsigned long long v) {
    unsigned lo = (unsigned)__builtin_amdgcn_update_dpp(
        (int)0xFFFFFFFFu, (int)(unsigned)v, CTRL, 0xF, 0xF, false);
    unsigned hi = (unsigned)__builtin_amdgcn_update_dpp(
        (int)0xFFFFFFFFu, (int)(unsigned)(v >> 32), CTRL, 0xF, 0xF, false);
    unsigned long long t = ((unsigned long long)hi << 32) | lo;
    return t < v ? t : v;
}
static __device__ __forceinline__ unsigned long long wave_min64_bcast(unsigned long long v) {
    v = dpp_min64_step<0x111>(v);
    v = dpp_min64_step<0x112>(v);
    v = dpp_min64_step<0x114>(v);
    v = dpp_min64_step<0x118>(v);
    v = dpp_min64_step<0x142>(v);
    v = dpp_min64_step<0x143>(v);
    unsigned lo = (unsigned)__builtin_amdgcn_readlane((int)(unsigned)v, 63);
    unsigned hi = (unsigned)__builtin_amdgcn_readlane((int)(unsigned)(v >> 32), 63);
    return ((unsigned long long)hi << 32) | lo;
}

// ---------------- knn: top-20 smallest distance indices (sq fused in) -------
// Block = 512 threads (8 waves) = (b, 8 queries); wave owns ONE query.
// Distance phase: thread t owns j in {4t..4t+3}; ONE float4 global load per
// channel; xq read as broadcast ds_read_b128 per 4 channels (was 8 scalar LDS
// reads per channel — the R9 issue bottleneck). sq_j accumulated inline from
// the same loads with the ascending-c fmaf(v,v,s) chain == sq_kernel's chain
// (bit-identical). sq_i computed by threads t<8 from staged xq, same chain.
// Selection (validated R8/R9): per-lane sorted top-4 queue of pk=(key<<12)|j
// in 4 named u64 regs; per round ONE u64 DPP-min chain; rare threshold refill.
// u64 min on distinct pk == exact (d, j) lexicographic — matches lax.top_k.
template<int C>
__global__ __launch_bounds__(512) void knn_kernel(const float* __restrict__ x,
                                                  int* __restrict__ idx) {
    const int QT = 8;
    __shared__ unsigned dl[QT][NN];   // 64 KB swizzled keys
    __shared__ float xq[QT][C];
    __shared__ float sqq[QT];
    int blk = blockIdx.x;
    int b = blk / (NN / QT);
    int q0 = (blk - b * (NN / QT)) * QT;
    int t = threadIdx.x;
    int lane = t & 63, wid = t >> 6;

    const float* xb = x + (size_t)b * C * NN;
    for (int e = t; e < QT * C; e += 512) {
        int q = e / C, c = e - q * C;
        xq[q][c] = xb[(size_t)c * NN + q0 + q];
    }
    __syncthreads();
    if (t < QT) {   // sq_i, identical chain to the old sq_kernel
        float s = 0.f;
        #pragma unroll 4
        for (int c = 0; c < C; ++c) s = fmaf(xq[t][c], xq[t][c], s);
        sqq[t] = s;
    }
    __syncthreads();

    float acc[QT][4];
    #pragma unroll
    for (int q = 0; q < QT; ++q)
        #pragma unroll
        for (int u = 0; u < 4; ++u) acc[q][u] = 0.f;
    float sqa0 = 0.f, sqa1 = 0.f, sqa2 = 0.f, sqa3 = 0.f;

    if constexpr (C % 4 == 0) {
        for (int c4 = 0; c4 < C; c4 += 4) {
            float4 xj0 = *(const float4*)&xb[(size_t)(c4 + 0) * NN + 4 * t];
            float4 xj1 = *(const float4*)&xb[(size_t)(c4 + 1) * NN + 4 * t];
            float4 xj2 = *(const float4*)&xb[(size_t)(c4 + 2) * NN + 4 * t];
            float4 xj3 = *(const float4*)&xb[(size_t)(c4 + 3) * NN + 4 * t];
            #pragma unroll
            for (int q = 0; q < QT; ++q) {
                float4 xqv = *(const float4*)&xq[q][c4];   // broadcast b128
                acc[q][0] = fmaf(xqv.x, xj0.x, acc[q][0]);
                acc[q][1] = fmaf(xqv.x, xj0.y, acc[q][1]);
                acc[q][2] = fmaf(xqv.x, xj0.z, acc[q][2]);
                acc[q][3] = fmaf(xqv.x, xj0.w, acc[q][3]);
                acc[q][0] = fmaf(xqv.y, xj1.x, acc[q][0]);
                acc[q][1] = fmaf(xqv.y, xj1.y, acc[q][1]);
                acc[q][2] = fmaf(xqv.y, xj1.z, acc[q][2]);
                acc[q][3] = fmaf(xqv.y, xj1.w, acc[q][3]);
                acc[q][0] = fmaf(xqv.z, xj2.x, acc[q][0]);
                acc[q][1] = fmaf(xqv.z, xj2.y, acc[q][1]);
                acc[q][2] = fmaf(xqv.z, xj2.z, acc[q][2]);
                acc[q][3] = fmaf(xqv.z, xj2.w, acc[q][3]);
                acc[q][0] = fmaf(xqv.w, xj3.x, acc[q][0]);
                acc[q][1] = fmaf(xqv.w, xj3.y, acc[q][1]);
                acc[q][2] = fmaf(xqv.w, xj3.z, acc[q][2]);
                acc[q][3] = fmaf(xqv.w, xj3.w, acc[q][3]);
            }
            // sq_j: ascending c within the quad — identical chain to sq_kernel
            sqa0 = fmaf(xj0.x, xj0.x, sqa0); sqa1 = fmaf(xj0.y, xj0.y, sqa1);
            sqa2 = fmaf(xj0.z, xj0.z, sqa2); sqa3 = fmaf(xj0.w, xj0.w, sqa3);
            sqa0 = fmaf(xj1.x, xj1.x, sqa0); sqa1 = fmaf(xj1.y, xj1.y, sqa1);
            sqa2 = fmaf(xj1.z, xj1.z, sqa2); sqa3 = fmaf(xj1.w, xj1.w, sqa3);
            sqa0 = fmaf(xj2.x, xj2.x, sqa0); sqa1 = fmaf(xj2.y, xj2.y, sqa1);
            sqa2 = fmaf(xj2.z, xj2.z, sqa2); sqa3 = fmaf(xj2.w, xj2.w, sqa3);
            sqa0 = fmaf(xj3.x, xj3.x, sqa0); sqa1 = fmaf(xj3.y, xj3.y, sqa1);
            sqa2 = fmaf(xj3.z, xj3.z, sqa2); sqa3 = fmaf(xj3.w, xj3.w, sqa3);
        }
    } else {
        for (int c = 0; c < C; ++c) {
            float4 xj = *(const float4*)&xb[(size_t)c * NN + 4 * t];
            #pragma unroll
            for (int q = 0; q < QT; ++q) {
                float xqc = xq[q][c];
                acc[q][0] = fmaf(xqc, xj.x, acc[q][0]);
                acc[q][1] = fmaf(xqc, xj.y, acc[q][1]);
                acc[q][2] = fmaf(xqc, xj.z, acc[q][2]);
                acc[q][3] = fmaf(xqc, xj.w, acc[q][3]);
            }
            sqa0 = fmaf(xj.x, xj.x, sqa0);
            sqa1 = fmaf(xj.y, xj.y, sqa1);
            sqa2 = fmaf(xj.z, xj.z, sqa2);
            sqa3 = fmaf(xj.w, xj.w, sqa3);
        }
    }
    float sqju[4] = {sqa0, sqa1, sqa2, sqa3};

    // d = sq_i + sq_j - 2*inner (bit-identical expression), monotone u32 key,
    // stored swizzled: j=4t+u -> word ((t>>3)<<5) | (((t^(t>>3))&7)<<2) | u
    int wbase = ((t >> 3) << 5) | (((t ^ (t >> 3)) & 7) << 2);
    #pragma unroll
    for (int q = 0; q < QT; ++q) {
        float sqi = sqq[q];
        uint4 kv;
        unsigned ks[4];
        #pragma unroll
        for (int u = 0; u < 4; ++u) {
            float d = sqi + sqju[u] - 2.f * acc[q][u];
            unsigned v = __float_as_uint(d);
            ks[u] = v ^ ((unsigned)((int)v >> 31) | 0x80000000u);
        }
        kv.x = ks[0]; kv.y = ks[1]; kv.z = ks[2]; kv.w = ks[3];
        *(uint4*)&dl[q][wbase] = kv;
    }
    __syncthreads();

    unsigned* dq = &dl[wid][0];
    int r7 = lane & 7;
    int lanebase = lane << 5;

    unsigned long long h0 = INFPK, h1 = INFPK, h2 = INFPK, h3 = INFPK;

#define PK_INS(KEY, LO) {                                                     \
        unsigned long long v =                                                \
            ((unsigned long long)(KEY) << 12) | (unsigned)(lanebase + (LO));  \
        if (v < h3) {                                                         \
            unsigned long long nh3 = h2 > v ? h2 : v;                         \
            unsigned long long t2  = h2 < v ? h2 : v;                         \
            unsigned long long nh2 = h1 > t2 ? h1 : t2;                       \
            unsigned long long t1  = h1 < v ? h1 : v;                         \
            unsigned long long nh1 = h0 > t1 ? h0 : t1;                       \
            unsigned long long nh0 = h0 < v ? h0 : v;                         \
            h0 = nh0; h1 = nh1; h2 = nh2; h3 = nh3;                           \
        } }
#define PK_INS_THR(KEY, LO) {                                                 \
        unsigned long long v =                                                \
            ((unsigned long long)(KEY) << 12) | (unsigned)(lanebase + (LO));  \
        if (v > thr && v < h3) {                                              \
            unsigned long long nh3 = h2 > v ? h2 : v;                         \
            unsigned long long t2  = h2 < v ? h2 : v;                         \
            unsigned long long nh2 = h1 > t2 ? h1 : t2;                       \
            unsigned long long t1  = h1 < v ? h1 : v;                         \
            unsigned long long nh1 = h0 > t1 ? h0 : t1;                       \
            unsigned long long nh0 = h0 < v ? h0 : v;                         \
            h0 = nh0; h1 = nh1; h2 = nh2; h3 = nh3;                           \
        } }
#define CHUNK_RD(c) uint4 V##c = *(const uint4*)(dq + lanebase + (((c) ^ r7) << 2));
#define CHUNK_INS(c)     { PK_INS(V##c.x, 4*(c)+0) PK_INS(V##c.y, 4*(c)+1)        \
                           PK_INS(V##c.z, 4*(c)+2) PK_INS(V##c.w, 4*(c)+3) }
#define CHUNK_INS_THR(c) { PK_INS_THR(V##c.x, 4*(c)+0) PK_INS_THR(V##c.y, 4*(c)+1) \
                           PK_INS_THR(V##c.z, 4*(c)+2) PK_INS_THR(V##c.w, 4*(c)+3) }

    {   // build: one pass over the lane's 32 candidates
        CHUNK_RD(0) CHUNK_RD(1) CHUNK_RD(2) CHUNK_RD(3)
        CHUNK_RD(4) CHUNK_RD(5) CHUNK_RD(6) CHUNK_RD(7)
        CHUNK_INS(0) CHUNK_INS(1) CHUNK_INS(2) CHUNK_INS(3)
        CHUNK_INS(4) CHUNK_INS(5) CHUNK_INS(6) CHUNK_INS(7)
    }

    int* orow = idx + (size_t)(b * NN + q0 + wid) * KK;
    unsigned long long thr = 0;
    int popped = 0;
    #pragma unroll 1
    for (int rr = 0; rr < KK; ++rr) {
        unsigned long long g = wave_min64_bcast(h0);
        if (lane == 0) orow[rr] = (int)(g & 0xFFFu);
        if (h0 == g) {
            thr = g;
            ++popped;
            h0 = h1; h1 = h2; h2 = h3; h3 = INFPK;
            if (h0 == INFPK && popped < 32) {   // rare refill
                CHUNK_RD(0) CHUNK_RD(1) CHUNK_RD(2) CHUNK_RD(3)
                CHUNK_RD(4) CHUNK_RD(5) CHUNK_RD(6) CHUNK_RD(7)
                CHUNK_INS_THR(0) CHUNK_INS_THR(1) CHUNK_INS_THR(2) CHUNK_INS_THR(3)
                CHUNK_INS_THR(4) CHUNK_INS_THR(5) CHUNK_INS_THR(6) CHUNK_INS_THR(7)
            }
        }
    }
#undef PK_INS
#undef PK_INS_THR
#undef CHUNK_RD
#undef CHUNK_INS
#undef CHUNK_INS_THR
}

// ---------------- p/t: p = Wn·x, t = (Wc-Wn)·x ----------------
template<int C, int OT>
__global__ __launch_bounds__(256) void pt_kernel(const float* __restrict__ x,
                                                 const float* __restrict__ W,
                                                 float* __restrict__ p,
                                                 float* __restrict__ tt,
                                                 int O) {
    const int NB = NN / 256;
    int blk = blockIdx.x;
    int nb = blk % NB;
    int rest = blk / NB;
    int nob = O / OT;
    int ob = rest % nob;
    int b = rest / nob;
    int t = threadIdx.x;
    int n = nb * 256 + t;
    __shared__ float wn[OT][C], wd[OT][C];
    for (int e = t; e < OT * C; e += 256) {
        int o = e / C, c = e - o * C;
        float a = W[(size_t)(ob * OT + o) * (2 * C) + c];
        float b2 = W[(size_t)(ob * OT + o) * (2 * C) + C + c];
        wn[o][c] = a;
        wd[o][c] = b2 - a;
    }
    __syncthreads();
    float ap[OT], at[OT];
    #pragma unroll
    for (int o = 0; o < OT; ++o) { ap[o] = 0.f; at[o] = 0.f; }
    const float* xb = x + (size_t)b * C * NN + n;
    for (int c = 0; c < C; ++c) {
        float xv = xb[(size_t)c * NN];
        #pragma unroll
        for (int o = 0; o < OT; ++o) {
            ap[o] = fmaf(wn[o][c], xv, ap[o]);
            at[o] = fmaf(wd[o][c], xv, at[o]);
        }
    }
    size_t base = ((size_t)b * O + ob * OT) * NN + n;
    #pragma unroll
    for (int o = 0; o < OT; ++o) {
        p[base + (size_t)o * NN] = ap[o];
        tt[base + (size_t)o * NN] = at[o];
    }
}

// ---------------- edge max: out[b,o,i] = max_k lrelu(scale*(p[j]+t_i)+beta) ----------------
__global__ __launch_bounds__(256) void edge_kernel(const float* __restrict__ p,
                                                   const float* __restrict__ tt,
                                                   const int* __restrict__ idx,
                                                   const float* __restrict__ g,
                                                   const float* __restrict__ be,
                                                   float* __restrict__ out, int O) {
    int b = blockIdx.x / O, o = blockIdx.x - b * O;
    __shared__ float pl[NN];
    const float* pr = p + ((size_t)b * O + o) * NN;
    for (int e = threadIdx.x * 4; e < NN; e += 1024)
        *(float4*)&pl[e] = *(const float4*)&pr[e];
    __syncthreads();
    float scale = g[o] / sqrtf(1.f + 1e-5f);
    float beta = be[o];
    const float* tr = tt + ((size_t)b * O + o) * NN;
    float* orow = out + ((size_t)b * O + o) * NN;
    for (int i = threadIdx.x; i < NN; i += 256) {
        float ti = tr[i];
        const int4* ir4 = (const int4*)(idx + (size_t)(b * NN + i) * KK);
        int4 w0 = ir4[0], w1 = ir4[1], w2 = ir4[2], w3 = ir4[3], w4 = ir4[4];
        float m = -__builtin_inff();
        int js[20] = {w0.x, w0.y, w0.z, w0.w, w1.x, w1.y, w1.z, w1.w,
                      w2.x, w2.y, w2.z, w2.w, w3.x, w3.y, w3.z, w3.w,
                      w4.x, w4.y, w4.z, w4.w};
        #pragma unroll
        for (int k = 0; k < KK; ++k) {
            float y = pl[js[k]] + ti;
            m = fmaxf(m, lrelu(fmaf(scale, y, beta)));
        }
        orow[i] = m;
    }
}

// ---------------- transpose W5 [1024][256] -> W5T [256][1024] ----------------
__global__ __launch_bounds__(256) void transpose_kernel(const float* __restrict__ W,
                                                        float* __restrict__ WT) {
    __shared__ float tile[32][33];
    int c0 = blockIdx.x * 32, o0 = blockIdx.y * 32;
    int tx = threadIdx.x, ty = threadIdx.y;   // 32 x 8
    #pragma unroll
    for (int i = 0; i < 32; i += 8)
        tile[ty + i][tx] = W[(size_t)(o0 + ty + i) * 256 + c0 + tx];
    __syncthreads();
    #pragma unroll
    for (int i = 0; i < 32; i += 8)
        WT[(size_t)(c0 + ty + i) * 1024 + o0 + tx] = tile[tx][ty + i];
}

// ---------------- final: register-tiled GEMM + fused lrelu + max over n ----------------
__global__ __launch_bounds__(256) void final_kernel(const float* __restrict__ x4,
                                                    const float* __restrict__ W5T,
                                                    const float* __restrict__ g,
                                                    const float* __restrict__ be,
                                                    float* __restrict__ partial) {
    const int CC = 256;
    __shared__ float xs[64][64];
    __shared__ float ws[64][64];
    int blk = blockIdx.x;
    int nb = blk & 31;
    int ob = (blk >> 5) & 15;
    int b  = blk >> 9;
    int t = threadIdx.x;
    int tn = t & 15, to = t >> 4;

    float acc[4][4];
    #pragma unroll
    for (int i = 0; i < 4; ++i)
        #pragma unroll
        for (int j = 0; j < 4; ++j) acc[i][j] = 0.f;

    for (int c0 = 0; c0 < CC; c0 += 64) {
        __syncthreads();
        #pragma unroll
        for (int e = t * 4; e < 64 * 64; e += 1024) {
            int c = e >> 6, n = e & 63;
            *(float4*)&xs[c][n] =
                *(const float4*)&x4[((size_t)b * CC + c0 + c) * NN + nb * 64 + n];
        }
        #pragma unroll
        for (int e = t * 4; e < 64 * 64; e += 1024) {
            int c = e >> 6, o = e & 63;
            *(float4*)&ws[c][o] =
                *(const float4*)&W5T[(size_t)(c0 + c) * 1024 + ob * 64 + o];
        }
        __syncthreads();
        for (int c = 0; c < 64; ++c) {
            float4 xv = *(float4*)&xs[c][tn * 4];
            float4 wv = *(float4*)&ws[c][to * 4];
            acc[0][0] = fmaf(wv.x, xv.x, acc[0][0]);
            acc[0][1] = fmaf(wv.x, xv.y, acc[0][1]);
            acc[0][2] = fmaf(wv.x, xv.z, acc[0][2]);
            acc[0][3] = fmaf(wv.x, xv.w, acc[0][3]);
            acc[1][0] = fmaf(wv.y, xv.x, acc[1][0]);
            acc[1][1] = fmaf(wv.y, xv.y, acc[1][1]);
            acc[1][2] = fmaf(wv.y, xv.z, acc[1][2]);
            acc[1][3] = fmaf(wv.y, xv.w, acc[1][3]);
            acc[2][0] = fmaf(wv.z, xv.x, acc[2][0]);
            acc[2][1] = fmaf(wv.z, xv.y, acc[2][1]);
            acc[2][2] = fmaf(wv.z, xv.z, acc[2][2]);
            acc[2][3] = fmaf(wv.z, xv.w, acc[2][3]);
            acc[3][0] = fmaf(wv.w, xv.x, acc[3][0]);
            acc[3][1] = fmaf(wv.w, xv.y, acc[3][1]);
            acc[3][2] = fmaf(wv.w, xv.z, acc[3][2]);
            acc[3][3] = fmaf(wv.w, xv.w, acc[3][3]);
        }
    }

    float rs = 1.f / sqrtf(1.f + 1e-5f);
    #pragma unroll
    for (int i = 0; i < 4; ++i) {
        int o = ob * 64 + to * 4 + i;
        float scale = g[o] * rs, beta = be[o];
        float m = -__builtin_inff();
        #pragma unroll
        for (int j = 0; j < 4; ++j)
            m = fmaxf(m, lrelu(fmaf(scale, acc[i][j], beta)));
        #pragma unroll
        for (int off = 8; off >= 1; off >>= 1)
            m = fmaxf(m, __shfl_xor(m, off));
        if (tn == 0)
            partial[(size_t)(nb * BB + b) * 1024 + o] = m;
    }
}

__global__ __launch_bounds__(256) void reduce32_kernel(const float* __restrict__ partial,
                                                       float* __restrict__ out) {
    int i = blockIdx.x * 256 + threadIdx.x;
    if (i >= BB * 1024) return;
    int b = i >> 10, o = i & 1023;
    float m = -__builtin_inff();
    #pragma unroll
    for (int nb = 0; nb < 32; ++nb)
        m = fmaxf(m, partial[(size_t)(nb * BB + b) * 1024 + o]);
    out[i] = m;
}

extern "C" void kernel_launch(void* const* d_in, const int* in_sizes, int n_in,
                              void* d_out, int out_size, void* d_ws, size_t ws_size,
                              hipStream_t stream) {
    const float* x  = (const float*)d_in[0];
    const float* W1 = (const float*)d_in[1];
    const float* g1 = (const float*)d_in[2];
    const float* b1 = (const float*)d_in[3];
    const float* W2 = (const float*)d_in[4];
    const float* g2 = (const float*)d_in[5];
    const float* b2 = (const float*)d_in[6];
    const float* W3 = (const float*)d_in[7];
    const float* g3 = (const float*)d_in[8];
    const float* b3 = (const float*)d_in[9];
    const float* W4 = (const float*)d_in[10];
    const float* g4 = (const float*)d_in[11];
    const float* b4 = (const float*)d_in[12];
    const float* W5 = (const float*)d_in[13];
    const float* g5 = (const float*)d_in[14];
    const float* b5 = (const float*)d_in[15];

    float* ws = (float*)d_ws;
    int*   idx     = (int*)(ws + 8192);        // 163840 ints (offset kept stable)
    float* x1      = ws + 8192 + 163840;       // 524288
    float* x2      = x1 + 524288;              // 524288
    float* x3      = x2 + 524288;              // 1048576
    float* x4      = x3 + 1048576;             // 2097152
    float* p       = x4 + 2097152;             // 2097152
    float* tt      = p + 2097152;              // 2097152
    float* W5T     = p;                        // reuse (dead after layer 4)
    float* partial = tt;                       // reuse

    dim3 blk(256), kblk(512);

    // ---- layer 1: C=3, O=64 ----
    knn_kernel<3><<<BB * (NN / 8), kblk, 0, stream>>>(x, idx);
    pt_kernel<3, 16><<<BB * (64 / 16) * (NN / 256), blk, 0, stream>>>(x, W1, p, tt, 64);
    edge_kernel<<<BB * 64, blk, 0, stream>>>(p, tt, idx, g1, b1, x1, 64);

    // ---- layer 2: C=64, O=64 ----
    knn_kernel<64><<<BB * (NN / 8), kblk, 0, stream>>>(x1, idx);
    pt_kernel<64, 16><<<BB * (64 / 16) * (NN / 256), blk, 0, stream>>>(x1, W2, p, tt, 64);
    edge_kernel<<<BB * 64, blk, 0, stream>>>(p, tt, idx, g2, b2, x2, 64);

    // ---- layer 3: C=64, O=128 ----
    knn_kernel<64><<<BB * (NN / 8), kblk, 0, stream>>>(x2, idx);
    pt_kernel<64, 16><<<BB * (128 / 16) * (NN / 256), blk, 0, stream>>>(x2, W3, p, tt, 128);
    edge_kernel<<<BB * 128, blk, 0, stream>>>(p, tt, idx, g3, b3, x3, 128);

    // ---- layer 4: C=128, O=256 ----
    knn_kernel<128><<<BB * (NN / 8), kblk, 0, stream>>>(x3, idx);
    pt_kernel<128, 16><<<BB * (256 / 16) * (NN / 256), blk, 0, stream>>>(x3, W4, p, tt, 256);
    edge_kernel<<<BB * 256, blk, 0, stream>>>(p, tt, idx, g4, b4, x4, 256);

    // ---- layer 5: C=256, O=1024, fused max over n ----
    transpose_kernel<<<dim3(8, 32), dim3(32, 8), 0, stream>>>(W5, W5T);
    final_kernel<<<BB * 16 * 32, blk, 0, stream>>>(x4, W5T, g5, b5, partial);
    reduce32_kernel<<<16, blk, 0, stream>>>(partial, (float*)d_out);
}